// Round 4
// baseline (118.168 us; speedup 1.0000x reference)
//
#include <hip/hip_runtime.h>
#include <math.h>

#define BATCH 2
#define RAYS  4096
#define NS    48
#define FEAT  32
#define HP    256
#define HID   64
#define NRAY  (BATCH*RAYS)
#define NSAMP (NRAY*NS)
#define S_DELTA (1.0f/47.0f)

__device__ __forceinline__ float softplus_f(float t) {
    float e = __expf(-fabsf(t));
    return fmaxf(t, 0.0f) + __logf(1.0f + e);
}
__device__ __forceinline__ float sigmoid_f(float t) {
    return 1.0f / (1.0f + __expf(-t));
}

// ---- gather helpers ----------------------------------------------------
// transposed layout: pT[bp][y][x][f], 32 floats contiguous per texel
__device__ __forceinline__ void corner_t(const float* __restrict__ base,
                                         int x, int y, float w, float4 acc[8]) {
    if ((unsigned)x < HP && (unsigned)y < HP) {
        const float4* p = (const float4*)(base + ((size_t)(y * HP + x) * FEAT));
        #pragma unroll
        for (int k = 0; k < 8; ++k) {
            float4 v = p[k];
            acc[k].x = fmaf(w, v.x, acc[k].x);
            acc[k].y = fmaf(w, v.y, acc[k].y);
            acc[k].z = fmaf(w, v.z, acc[k].z);
            acc[k].w = fmaf(w, v.w, acc[k].w);
        }
    }
}
__device__ __forceinline__ void corner_d(const float* __restrict__ base,
                                         int x, int y, float w, float4 acc[8]) {
    if ((unsigned)x < HP && (unsigned)y < HP) {
        const float* p = base + ((size_t)y * HP + x);
        #pragma unroll
        for (int k = 0; k < 8; ++k) {
            float* a = &acc[k].x;
            #pragma unroll
            for (int c = 0; c < 4; ++c) {
                float v = p[(size_t)(k * 4 + c) * (HP * HP)];
                a[c] = fmaf(w, v, a[c]);
            }
        }
    }
}

template<bool TRANS>
__device__ __forceinline__ void sample_plane(const float* __restrict__ base,
                                             float gx, float gy, float4 acc[8]) {
    float px = (gx + 1.0f) * 0.5f * (float)(HP - 1);
    float py = (gy + 1.0f) * 0.5f * (float)(HP - 1);
    float fx = floorf(px), fy = floorf(py);
    float wx = px - fx,    wy = py - fy;
    int x0 = (int)fx, y0 = (int)fy;
    int x1 = x0 + 1,  y1 = y0 + 1;
    float w00 = (1.0f - wx) * (1.0f - wy);
    float w10 = wx * (1.0f - wy);
    float w01 = (1.0f - wx) * wy;
    float w11 = wx * wy;
    if (TRANS) {
        corner_t(base, x0, y0, w00, acc);
        corner_t(base, x1, y0, w10, acc);
        corner_t(base, x0, y1, w01, acc);
        corner_t(base, x1, y1, w11, acc);
    } else {
        corner_d(base, x0, y0, w00, acc);
        corner_d(base, x1, y0, w10, acc);
        corner_d(base, x0, y1, w01, acc);
        corner_d(base, x1, y1, w11, acc);
    }
}

// ---- transpose planes [B*3,F,H,W] -> [B*3,H,W,F]; also W1 -> W1T -------
__global__ __launch_bounds__(256)
void transpose_planes_w(const float* __restrict__ planes,
                        const float* __restrict__ W1,
                        float* __restrict__ pT, float* __restrict__ W1T) {
    int idx = blockIdx.x * 256 + threadIdx.x;
    const int total = BATCH * 3 * HP * HP;
    if (idx < total) {
        int xy = idx % (HP * HP);
        int bp = idx / (HP * HP);
        const float* src = planes + (size_t)bp * FEAT * HP * HP + xy;
        float4 v[8];
        #pragma unroll
        for (int k = 0; k < 8; ++k) {
            v[k].x = src[(size_t)(4 * k + 0) * HP * HP];
            v[k].y = src[(size_t)(4 * k + 1) * HP * HP];
            v[k].z = src[(size_t)(4 * k + 2) * HP * HP];
            v[k].w = src[(size_t)(4 * k + 3) * HP * HP];
        }
        float4* dst = (float4*)(pT + (size_t)idx * FEAT);
        #pragma unroll
        for (int k = 0; k < 8; ++k) dst[k] = v[k];
    } else {
        int r = idx - total;               // 0..255 (one extra block)
        #pragma unroll
        for (int k = 0; k < 8; ++k) {
            int e = r * 8 + k;             // 0..2047
            int j = e >> 5, f = e & 31;
            W1T[e] = W1[f * HID + j];      // W1T[j][f] contiguous rows
        }
    }
}

// legacy transpose (no W1T) for the mid-size-ws fallback path
__global__ __launch_bounds__(256)
void transpose_planes(const float* __restrict__ planes, float* __restrict__ pT) {
    int idx = blockIdx.x * 256 + threadIdx.x;
    int xy = idx % (HP * HP);
    int bp = idx / (HP * HP);
    const float* src = planes + (size_t)bp * FEAT * HP * HP + xy;
    float4 v[8];
    #pragma unroll
    for (int k = 0; k < 8; ++k) {
        v[k].x = src[(size_t)(4 * k + 0) * HP * HP];
        v[k].y = src[(size_t)(4 * k + 1) * HP * HP];
        v[k].z = src[(size_t)(4 * k + 2) * HP * HP];
        v[k].w = src[(size_t)(4 * k + 3) * HP * HP];
    }
    float4* dst = (float4*)(pT + (size_t)idx * FEAT);
    #pragma unroll
    for (int k = 0; k < 8; ++k) dst[k] = v[k];
}

// ---- phase 1: gather + MLP, one thread per sample ----------------------
__global__ __launch_bounds__(256)
void sample_mlp(const float* __restrict__ pT,
                const float* __restrict__ rayo,
                const float* __restrict__ rayd,
                const float* __restrict__ jitter,
                const float* __restrict__ W1T, const float* __restrict__ b1,
                const float* __restrict__ W2,  const float* __restrict__ b2,
                float4* __restrict__ smp, float* __restrict__ sds) {
    unsigned tid = blockIdx.x * 256 + threadIdx.x;     // sample index
    unsigned ray = tid / NS;
    unsigned n   = tid - ray * NS;
    unsigned b   = ray >> 12;

    float jit = jitter[tid];
    float sd  = fmaf((float)n, S_DELTA, jit * S_DELTA);

    float ox = rayo[ray * 3 + 0], oy = rayo[ray * 3 + 1], oz = rayo[ray * 3 + 2];
    float dx = rayd[ray * 3 + 0], dy = rayd[ray * 3 + 1], dz = rayd[ray * 3 + 2];
    float cx = fmaf(sd, dx, ox);
    float cy = fmaf(sd, dy, oy);
    float cz = fmaf(sd, dz, oz);

    float4 acc[8];
    #pragma unroll
    for (int k = 0; k < 8; ++k) acc[k] = make_float4(0.f, 0.f, 0.f, 0.f);

    const size_t psz = (size_t)HP * HP * FEAT;
    const float* base = pT + (size_t)b * 3 * psz;
    sample_plane<true>(base,           cx, cy, acc);
    sample_plane<true>(base + psz,     cx, cz, acc);
    sample_plane<true>(base + 2 * psz, cy, cz, acc);

    float xv[32];
    #pragma unroll
    for (int k = 0; k < 8; ++k) {
        xv[4 * k + 0] = acc[k].x * (1.0f / 3.0f);
        xv[4 * k + 1] = acc[k].y * (1.0f / 3.0f);
        xv[4 * k + 2] = acc[k].z * (1.0f / 3.0f);
        xv[4 * k + 3] = acc[k].w * (1.0f / 3.0f);
    }

    // j-outer MLP: W1T rows contiguous -> wide scalar loads
    float o0 = b2[0], o1 = b2[1], o2 = b2[2], o3 = b2[3];
    #pragma unroll
    for (int j = 0; j < HID; ++j) {
        float hj = b1[j];
        const float* wr = W1T + j * FEAT;
        #pragma unroll
        for (int f = 0; f < FEAT; ++f) hj = fmaf(xv[f], wr[f], hj);
        hj = softplus_f(hj);
        o0 = fmaf(hj, W2[j * 4 + 0], o0);
        o1 = fmaf(hj, W2[j * 4 + 1], o1);
        o2 = fmaf(hj, W2[j * 4 + 2], o2);
        o3 = fmaf(hj, W2[j * 4 + 3], o3);
    }

    smp[tid] = make_float4(softplus_f(o0),               // dens
                           sigmoid_f(o1) * 1.002f - 0.001f,
                           sigmoid_f(o2) * 1.002f - 0.001f,
                           sigmoid_f(o3) * 1.002f - 0.001f);
    sds[tid] = sd;
}

// ---- phase 2: wave-per-ray composite (log-space prefix scan) -----------
__global__ __launch_bounds__(256)
void composite(const float4* __restrict__ smp, const float* __restrict__ sds,
               float* __restrict__ out) {
    int w    = threadIdx.x >> 6;
    int lane = threadIdx.x & 63;
    int ray  = blockIdx.x * 4 + w;
    int base = ray * NS;
    bool valid = lane < NS;

    float4 v = make_float4(0.f, 0.f, 0.f, 0.f);
    float sd = 0.f;
    if (valid) { v = smp[base + lane]; sd = sds[base + lane]; }
    float sdn = __shfl_down(sd, 1);

    float alpha = 0.f, l = 0.f;
    if (valid) {
        float delta = (lane < NS - 1) ? (sdn - sd) : 1e10f;
        float t = __expf(-delta * v.x);
        alpha = 1.0f - t;
        l = __logf(t + 1e-10f);          // log(1 - alpha + EPS)
    }

    // inclusive prefix sum of l across lanes
    float s = l;
    #pragma unroll
    for (int off = 1; off < 64; off <<= 1) {
        float u = __shfl_up(s, off);
        if (lane >= off) s += u;
    }
    float finalLog = __shfl(s, NS - 1);   // log of full cumprod
    float T   = __expf(s - l);            // exclusive cumprod
    float wgt = valid ? alpha * T : 0.f;

    float rf = wgt * v.y, gf = wgt * v.z, bf = wgt * v.w;
    float dep = wgt * sd, wsum = wgt;
    #pragma unroll
    for (int off = 32; off; off >>= 1) {
        rf   += __shfl_xor(rf, off);
        gf   += __shfl_xor(gf, off);
        bf   += __shfl_xor(bf, off);
        dep  += __shfl_xor(dep, off);
        wsum += __shfl_xor(wsum, off);
    }
    if (lane == 0) {
        out[ray * 3 + 0] = rf;
        out[ray * 3 + 1] = gf;
        out[ray * 3 + 2] = bf;
        out[NRAY * 3 + ray] = dep;
        out[NRAY * 4 + ray] = wsum;
        out[NRAY * 5 + ray] = __expf(finalLog);
    }
}

// ---- fallback: fully fused (round-1 kernel) ----------------------------
template<bool TRANS>
__global__ __launch_bounds__(192)
void render_kernel(const float* __restrict__ pl,
                   const float* __restrict__ rayo,
                   const float* __restrict__ rayd,
                   const float* __restrict__ jitter,
                   const float* __restrict__ W1, const float* __restrict__ b1,
                   const float* __restrict__ W2, const float* __restrict__ b2,
                   float* __restrict__ out) {
    __shared__ float4 smp[192];
    __shared__ float  sdsb[192];
    int tid = threadIdx.x;
    int lr  = tid / NS;
    int n   = tid - lr * NS;
    int ray = blockIdx.x * 4 + lr;
    int b   = ray >> 12;

    float jit = jitter[ray * NS + n];
    float sd  = (float)n * S_DELTA + jit * S_DELTA;
    float ox = rayo[ray * 3 + 0], oy = rayo[ray * 3 + 1], oz = rayo[ray * 3 + 2];
    float dx = rayd[ray * 3 + 0], dy = rayd[ray * 3 + 1], dz = rayd[ray * 3 + 2];
    float cx = fmaf(sd, dx, ox), cy = fmaf(sd, dy, oy), cz = fmaf(sd, dz, oz);

    float4 acc[8];
    #pragma unroll
    for (int k = 0; k < 8; ++k) acc[k] = make_float4(0.f, 0.f, 0.f, 0.f);
    const size_t psz = (size_t)HP * HP * FEAT;
    const float* base = pl + (size_t)b * 3 * psz;
    sample_plane<TRANS>(base,           cx, cy, acc);
    sample_plane<TRANS>(base + psz,     cx, cz, acc);
    sample_plane<TRANS>(base + 2 * psz, cy, cz, acc);

    float xv[32];
    #pragma unroll
    for (int k = 0; k < 8; ++k) {
        xv[4 * k + 0] = acc[k].x * (1.0f / 3.0f);
        xv[4 * k + 1] = acc[k].y * (1.0f / 3.0f);
        xv[4 * k + 2] = acc[k].z * (1.0f / 3.0f);
        xv[4 * k + 3] = acc[k].w * (1.0f / 3.0f);
    }
    float o0 = b2[0], o1 = b2[1], o2 = b2[2], o3 = b2[3];
    #pragma unroll
    for (int j = 0; j < HID; ++j) {
        float hj = b1[j];
        #pragma unroll
        for (int f = 0; f < FEAT; ++f) hj = fmaf(xv[f], W1[f * HID + j], hj);
        hj = softplus_f(hj);
        o0 = fmaf(hj, W2[j * 4 + 0], o0);
        o1 = fmaf(hj, W2[j * 4 + 1], o1);
        o2 = fmaf(hj, W2[j * 4 + 2], o2);
        o3 = fmaf(hj, W2[j * 4 + 3], o3);
    }
    smp[tid] = make_float4(softplus_f(o0),
                           sigmoid_f(o1) * 1.002f - 0.001f,
                           sigmoid_f(o2) * 1.002f - 0.001f,
                           sigmoid_f(o3) * 1.002f - 0.001f);
    sdsb[tid] = sd;
    __syncthreads();

    if (tid < 4) {
        int rray = blockIdx.x * 4 + tid;
        const float4* sp  = &smp[tid * NS];
        const float*  sdp = &sdsb[tid * NS];
        float T = 1.0f, rf = 0.f, gf = 0.f, bfv = 0.f, dep = 0.f, wsum = 0.f;
        for (int m = 0; m < NS; ++m) {
            float4 vv = sp[m];
            float sdc = sdp[m];
            float delta = (m < NS - 1) ? (sdp[m + 1] - sdc) : 1e10f;
            float alpha = 1.0f - __expf(-delta * vv.x);
            float wq = alpha * T;
            rf = fmaf(wq, vv.y, rf);
            gf = fmaf(wq, vv.z, gf);
            bfv = fmaf(wq, vv.w, bfv);
            dep = fmaf(wq, sdc, dep);
            wsum += wq;
            T *= (1.0f - alpha + 1e-10f);
        }
        out[rray * 3 + 0] = rf;
        out[rray * 3 + 1] = gf;
        out[rray * 3 + 2] = bfv;
        out[NRAY * 3 + rray] = dep;
        out[NRAY * 4 + rray] = wsum;
        out[NRAY * 5 + rray] = T;
    }
}

extern "C" void kernel_launch(void* const* d_in, const int* in_sizes, int n_in,
                              void* d_out, int out_size, void* d_ws, size_t ws_size,
                              hipStream_t stream) {
    const float* planes = (const float*)d_in[0];
    const float* rayo   = (const float*)d_in[1];
    const float* rayd   = (const float*)d_in[2];
    const float* jitter = (const float*)d_in[3];
    const float* W1     = (const float*)d_in[4];
    const float* b1     = (const float*)d_in[5];
    const float* W2     = (const float*)d_in[6];
    const float* b2     = (const float*)d_in[7];
    float* out = (float*)d_out;

    const size_t pT_bytes  = (size_t)BATCH * 3 * HP * HP * FEAT * sizeof(float); // 50.3 MB
    const size_t w1t_off   = pT_bytes;
    const size_t smp_off   = w1t_off + (size_t)FEAT * HID * sizeof(float);
    const size_t sds_off   = smp_off + (size_t)NSAMP * sizeof(float4);
    const size_t need      = sds_off + (size_t)NSAMP * sizeof(float);

    if (ws_size >= need) {
        char* ws = (char*)d_ws;
        float*  pT  = (float*)ws;
        float*  W1T = (float*)(ws + w1t_off);
        float4* smp = (float4*)(ws + smp_off);
        float*  sds = (float*)(ws + sds_off);
        const int tgrid = BATCH * 3 * HP * HP / 256 + 1;
        hipLaunchKernelGGL(transpose_planes_w, dim3(tgrid), dim3(256), 0, stream,
                           planes, W1, pT, W1T);
        hipLaunchKernelGGL(sample_mlp, dim3(NSAMP / 256), dim3(256), 0, stream,
                           pT, rayo, rayd, jitter, W1T, b1, W2, b2, smp, sds);
        hipLaunchKernelGGL(composite, dim3(NRAY / 4), dim3(256), 0, stream,
                           smp, sds, out);
    } else if (ws_size >= pT_bytes) {
        float* pT = (float*)d_ws;
        hipLaunchKernelGGL(transpose_planes, dim3(BATCH * 3 * HP * HP / 256), dim3(256),
                           0, stream, planes, pT);
        hipLaunchKernelGGL((render_kernel<true>), dim3(NRAY / 4), dim3(192), 0, stream,
                           pT, rayo, rayd, jitter, W1, b1, W2, b2, out);
    } else {
        hipLaunchKernelGGL((render_kernel<false>), dim3(NRAY / 4), dim3(192), 0, stream,
                           planes, rayo, rayd, jitter, W1, b1, W2, b2, out);
    }
}

// Round 7
// 64.642 us; speedup vs baseline: 1.8280x; 1.8280x over previous
//
#include <hip/hip_runtime.h>
#include <math.h>

#define BATCH 2
#define RAYS  4096
#define NS    48
#define FEAT  32
#define HP    256
#define HID   64
#define NRAY  (BATCH*RAYS)
#define NSAMP (NRAY*NS)
#define S_DELTA (1.0f/47.0f)

typedef unsigned short u16;
typedef __attribute__((ext_vector_type(8))) short bfrag8;   // 8 bf16 (4 VGPRs)
typedef __attribute__((ext_vector_type(4))) float facc4;    // 4 f32 accum

__device__ __forceinline__ float softplus_f(float t) {
    float e = __expf(-fabsf(t));
    return fmaxf(t, 0.0f) + __logf(1.0f + e);
}
__device__ __forceinline__ float sigmoid_f(float t) {
    return 1.0f / (1.0f + __expf(-t));
}
// f32 -> bf16 round-to-nearest-even (bit trick)
__device__ __forceinline__ unsigned rtne16(float f) {
    unsigned u = __float_as_uint(f);
    return (u + 0x7FFFu + ((u >> 16) & 1u)) >> 16;
}

// ---- prep: planes f32 [bp][f][y][x] -> bf16 [bp][y][x][f]; W1,W2 -> B-frag order
__global__ __launch_bounds__(256)
void prep_kernel(const float* __restrict__ planes,
                 const float* __restrict__ W1,
                 const float* __restrict__ W2,
                 u16* __restrict__ pT,
                 u16* __restrict__ W1F,
                 u16* __restrict__ W2F) {
    int idx = blockIdx.x * 256 + threadIdx.x;
    const int total = BATCH * 3 * HP * HP;
    if (idx < total) {
        int xy = idx % (HP * HP);
        int bp = idx / (HP * HP);
        const float* src = planes + (size_t)bp * FEAT * HP * HP + xy;
        unsigned o16[16];
        #pragma unroll
        for (int k = 0; k < 16; ++k) {
            float v0 = src[(size_t)(2 * k) * HP * HP];
            float v1 = src[(size_t)(2 * k + 1) * HP * HP];
            o16[k] = rtne16(v0) | (rtne16(v1) << 16);
        }
        uint4* dst = (uint4*)(pT + (size_t)idx * FEAT);
        #pragma unroll
        for (int q = 0; q < 4; ++q)
            dst[q] = make_uint4(o16[4*q], o16[4*q+1], o16[4*q+2], o16[4*q+3]);
    } else {
        int r = idx - total;              // 0..255 (one tail block)
        // W1F: B-frag of W1[32 k][64 n]; entry e=(nt*64+l)*8+i holds
        // bf16(W1[k= (l>>4)*8+i ][ n= nt*16+(l&15) ])
        #pragma unroll
        for (int i = 0; i < 8; ++i) {
            int e = r * 8 + i;            // 0..2047
            int nt = e >> 9, ll = (e >> 3) & 63, ii = e & 7;
            int k = ((ll >> 4) << 3) + ii;
            int nn = (nt << 4) + (ll & 15);
            W1F[e] = (u16)rtne16(W1[k * HID + nn]);
        }
        // W2F: B-frag of W2 padded [64 k][16 n]; e=(kk*64+l)*8+i holds
        // bf16(W2[k= kk*32+(l>>4)*8+i ][ n=l&15 ]) (n>=4 -> 0)
        if (r < 128) {
            #pragma unroll
            for (int i = 0; i < 8; ++i) {
                int e = r * 8 + i;        // 0..1023
                int kk = e >> 9, ll = (e >> 3) & 63, ii = e & 7;
                int k = kk * 32 + ((ll >> 4) << 3) + ii;
                int nn = ll & 15;
                W2F[e] = (nn < 4) ? (u16)rtne16(W2[k * 4 + nn]) : (u16)0;
            }
        }
    }
}

// ---- gather helpers (bf16 texels, per-lane 8-feature chunk) ------------
__device__ __forceinline__ void corner_bf16(const u16* __restrict__ p,
                                            float w, float acc[8]) {
    uint4 q = *(const uint4*)p;
    unsigned uu[4] = {q.x, q.y, q.z, q.w};
    #pragma unroll
    for (int i = 0; i < 4; ++i) {
        float lo = __uint_as_float(uu[i] << 16);
        float hi = __uint_as_float(uu[i] & 0xFFFF0000u);
        acc[2*i]   = fmaf(w, lo, acc[2*i]);
        acc[2*i+1] = fmaf(w, hi, acc[2*i+1]);
    }
}

__device__ __forceinline__ void gather_plane_bf16(const u16* __restrict__ pb,
                                                  float gx, float gy, int fc8,
                                                  float acc[8]) {
    float px = (gx + 1.0f) * 0.5f * (float)(HP - 1);
    float py = (gy + 1.0f) * 0.5f * (float)(HP - 1);
    float fx = floorf(px), fy = floorf(py);
    float wx = px - fx, wy = py - fy;
    int x0 = (int)fx, y0 = (int)fy;
    int x1 = x0 + 1, y1 = y0 + 1;
    bool vx0 = (unsigned)x0 < HP, vx1 = (unsigned)x1 < HP;
    bool vy0 = (unsigned)y0 < HP, vy1 = (unsigned)y1 < HP;
    int cx0 = min(max(x0, 0), HP-1), cx1 = min(max(x1, 0), HP-1);
    int cy0 = min(max(y0, 0), HP-1), cy1 = min(max(y1, 0), HP-1);
    float w00 = (vx0 && vy0) ? (1.f-wx)*(1.f-wy) : 0.f;
    float w10 = (vx1 && vy0) ? wx*(1.f-wy)       : 0.f;
    float w01 = (vx0 && vy1) ? (1.f-wx)*wy       : 0.f;
    float w11 = (vx1 && vy1) ? wx*wy             : 0.f;
    corner_bf16(pb + ((size_t)(cy0*HP + cx0)*FEAT + fc8), w00, acc);
    corner_bf16(pb + ((size_t)(cy0*HP + cx1)*FEAT + fc8), w10, acc);
    corner_bf16(pb + ((size_t)(cy1*HP + cx0)*FEAT + fc8), w01, acc);
    corner_bf16(pb + ((size_t)(cy1*HP + cx1)*FEAT + fc8), w11, acc);
}

// ---- phase 1: gather + MFMA MLP. wave = 16 samples x 4 feat-chunks -----
// lane l: sample = base+(l&15), feats (l>>4)*8..+7  == A-frag layout of
// mfma_f32_16x16x32_bf16 (row=l&15, k=(l>>4)*8+i). C/D: row=4*(l>>4)+reg,
// col=l&15 (guide-verified m89/m91).
__global__ __launch_bounds__(256)
void sample_mlp_mfma(const u16* __restrict__ pT,
                     const float* __restrict__ rayo,
                     const float* __restrict__ rayd,
                     const float* __restrict__ jitter,
                     const u16* __restrict__ W1F,
                     const u16* __restrict__ W2F,
                     const float* __restrict__ b1,
                     const float* __restrict__ b2,
                     float4* __restrict__ smp, float* __restrict__ sds) {
    __shared__ __align__(16) u16 hlds[4][1024];   // per-wave 16x64 bf16, XOR-swizzled
    const int t = threadIdx.x;
    const int w = t >> 6;
    const int l = t & 63;
    const int c = l & 15;          // A-row / C-col
    const int g = l >> 4;          // k-chunk / C row-group
    const int sbase = (blockIdx.x * 4 + w) * 16;
    const int s = sbase + c;       // this lane's gather sample
    const int ray = s / NS;
    const int n = s - ray * NS;
    const int b = ray >> 12;

    const float jit = jitter[s];
    const float sd = fmaf((float)n, S_DELTA, jit * S_DELTA);
    const float ox = rayo[ray*3+0], oy = rayo[ray*3+1], oz = rayo[ray*3+2];
    const float dx = rayd[ray*3+0], dy = rayd[ray*3+1], dz = rayd[ray*3+2];
    const float cxv = fmaf(sd, dx, ox);
    const float cyv = fmaf(sd, dy, oy);
    const float czv = fmaf(sd, dz, oz);

    float acc[8];
    #pragma unroll
    for (int i = 0; i < 8; ++i) acc[i] = 0.f;

    const int fc8 = g * 8;
    const u16* base = pT + (size_t)b * 3 * HP * HP * FEAT;
    gather_plane_bf16(base,                         cxv, cyv, fc8, acc);  // (x,y)
    gather_plane_bf16(base + (size_t)HP*HP*FEAT,    cxv, czv, fc8, acc);  // (x,z)
    gather_plane_bf16(base + 2*(size_t)HP*HP*FEAT,  cyv, czv, fc8, acc);  // (y,z)

    // mean over 3 planes -> bf16 A-frag
    union { unsigned u[4]; bfrag8 v; } A;
    #pragma unroll
    for (int p = 0; p < 4; ++p)
        A.u[p] = rtne16(acc[2*p] * (1.f/3.f)) |
                 (rtne16(acc[2*p+1] * (1.f/3.f)) << 16);

    // layer 1: H[16 samples][64 hid] = X @ W1   (4 MFMAs over n-tiles)
    const facc4 z4 = {0.f, 0.f, 0.f, 0.f};
    facc4 H[4];
    #pragma unroll
    for (int nt = 0; nt < 4; ++nt) {
        union { uint4 q; bfrag8 v; } B;
        B.q = *(const uint4*)(W1F + (size_t)(nt * 64 + l) * 8);
        H[nt] = __builtin_amdgcn_mfma_f32_16x16x32_bf16(A.v, B.v, z4, 0, 0, 0);
    }

    // bias + softplus -> bf16 -> LDS (XOR swizzle: byte ^= (row&7)<<4)
    char* lb = (char*)&hlds[w][0];
    #pragma unroll
    for (int nt = 0; nt < 4; ++nt) {
        const float bb = b1[nt * 16 + c];
        #pragma unroll
        for (int r = 0; r < 4; ++r) {
            const int row = g * 4 + r;                  // sample-in-wave
            const float hv = softplus_f(H[nt][r] + bb);
            const int off = row * 128 + ((((nt * 16 + c) * 2)) ^ ((row & 7) << 4));
            *(u16*)(lb + off) = (u16)rtne16(hv);
        }
    }
    // wave-private LDS: compiler inserts lgkmcnt wait; no barrier needed.

    // layer 2: O[16][4] = softplus(H) @ W2   (2 MFMAs over K=64)
    facc4 O = z4;
    #pragma unroll
    for (int kk = 0; kk < 2; ++kk) {
        union { uint4 q; bfrag8 v; } A2;
        const int off = c * 128 + ((kk * 64 + g * 16) ^ ((c & 7) << 4));
        A2.q = *(const uint4*)(lb + off);
        union { uint4 q; bfrag8 v; } B2;
        B2.q = *(const uint4*)(W2F + (size_t)(kk * 64 + l) * 8);
        O = __builtin_amdgcn_mfma_f32_16x16x32_bf16(A2.v, B2.v, O, 0, 0, 0);
    }

    // epilogue: lane holds O[sample 4g+r][col c]; cols 0..3 valid
    if (c < 4) {
        const float bb = b2[c];
        #pragma unroll
        for (int r = 0; r < 4; ++r) {
            const int ss = sbase + g * 4 + r;
            const float o = O[r] + bb;
            const float val = (c == 0) ? softplus_f(o)
                                       : (sigmoid_f(o) * 1.002f - 0.001f);
            ((float*)&smp[ss])[c] = val;
        }
    }
    if (g == 0) sds[s] = sd;
}

// ---- phase 2: wave-per-ray composite (log-space prefix scan) -----------
__global__ __launch_bounds__(256)
void composite(const float4* __restrict__ smp, const float* __restrict__ sds,
               float* __restrict__ out) {
    int w    = threadIdx.x >> 6;
    int lane = threadIdx.x & 63;
    int ray  = blockIdx.x * 4 + w;
    int base = ray * NS;
    bool valid = lane < NS;

    float4 v = make_float4(0.f, 0.f, 0.f, 0.f);
    float sd = 0.f;
    if (valid) { v = smp[base + lane]; sd = sds[base + lane]; }
    float sdn = __shfl_down(sd, 1);

    float alpha = 0.f, l = 0.f;
    if (valid) {
        float delta = (lane < NS - 1) ? (sdn - sd) : 1e10f;
        float tt = __expf(-delta * v.x);
        alpha = 1.0f - tt;
        l = __logf(tt + 1e-10f);
    }
    float sacc = l;
    #pragma unroll
    for (int off = 1; off < 64; off <<= 1) {
        float u = __shfl_up(sacc, off);
        if (lane >= off) sacc += u;
    }
    float finalLog = __shfl(sacc, NS - 1);
    float T   = __expf(sacc - l);
    float wgt = valid ? alpha * T : 0.f;

    float rf = wgt * v.y, gf = wgt * v.z, bf = wgt * v.w;
    float dep = wgt * sd, wsum = wgt;
    #pragma unroll
    for (int off = 32; off; off >>= 1) {
        rf   += __shfl_xor(rf, off);
        gf   += __shfl_xor(gf, off);
        bf   += __shfl_xor(bf, off);
        dep  += __shfl_xor(dep, off);
        wsum += __shfl_xor(wsum, off);
    }
    if (lane == 0) {
        out[ray * 3 + 0] = rf;
        out[ray * 3 + 1] = gf;
        out[ray * 3 + 2] = bf;
        out[NRAY * 3 + ray] = dep;
        out[NRAY * 4 + ray] = wsum;
        out[NRAY * 5 + ray] = __expf(finalLog);
    }
}

// ---- fallback: fully fused fp32, direct plane layout (from round 1) ----
__global__ __launch_bounds__(192)
void render_fused(const float* __restrict__ pl,
                  const float* __restrict__ rayo,
                  const float* __restrict__ rayd,
                  const float* __restrict__ jitter,
                  const float* __restrict__ W1, const float* __restrict__ b1,
                  const float* __restrict__ W2, const float* __restrict__ b2,
                  float* __restrict__ out) {
    __shared__ float4 smpb[192];
    __shared__ float  sdsb[192];
    int tid = threadIdx.x;
    int lr  = tid / NS;
    int n   = tid - lr * NS;
    int ray = blockIdx.x * 4 + lr;
    int b   = ray >> 12;

    float jit = jitter[ray * NS + n];
    float sd  = (float)n * S_DELTA + jit * S_DELTA;
    float ox = rayo[ray*3+0], oy = rayo[ray*3+1], oz = rayo[ray*3+2];
    float dx = rayd[ray*3+0], dy = rayd[ray*3+1], dz = rayd[ray*3+2];
    float cx = fmaf(sd, dx, ox), cy = fmaf(sd, dy, oy), cz = fmaf(sd, dz, oz);

    float xv[32];
    #pragma unroll
    for (int i = 0; i < 32; ++i) xv[i] = 0.f;
    const size_t psz = (size_t)HP * HP * FEAT;
    const float* base = pl + (size_t)b * 3 * psz;
    float gxs[3] = {cx, cx, cy}, gys[3] = {cy, cz, cz};
    for (int p = 0; p < 3; ++p) {
        float px = (gxs[p] + 1.0f) * 0.5f * (float)(HP - 1);
        float py = (gys[p] + 1.0f) * 0.5f * (float)(HP - 1);
        float fx = floorf(px), fy = floorf(py);
        float wx = px - fx, wy = py - fy;
        int x0 = (int)fx, y0 = (int)fy, x1 = x0 + 1, y1 = y0 + 1;
        const float* pb = base + p * psz;
        float ws[4] = {(1.f-wx)*(1.f-wy), wx*(1.f-wy), (1.f-wx)*wy, wx*wy};
        int xs[4] = {x0, x1, x0, x1}, ys[4] = {y0, y0, y1, y1};
        for (int q = 0; q < 4; ++q) {
            if ((unsigned)xs[q] < HP && (unsigned)ys[q] < HP) {
                const float* pp = pb + (size_t)ys[q] * HP + xs[q];
                #pragma unroll
                for (int f = 0; f < 32; ++f)
                    xv[f] = fmaf(ws[q], pp[(size_t)f * HP * HP], xv[f]);
            }
        }
    }
    #pragma unroll
    for (int i = 0; i < 32; ++i) xv[i] *= (1.f/3.f);

    float o0 = b2[0], o1 = b2[1], o2 = b2[2], o3 = b2[3];
    #pragma unroll
    for (int j = 0; j < HID; ++j) {
        float hj = b1[j];
        #pragma unroll
        for (int f = 0; f < FEAT; ++f) hj = fmaf(xv[f], W1[f * HID + j], hj);
        hj = softplus_f(hj);
        o0 = fmaf(hj, W2[j*4+0], o0);
        o1 = fmaf(hj, W2[j*4+1], o1);
        o2 = fmaf(hj, W2[j*4+2], o2);
        o3 = fmaf(hj, W2[j*4+3], o3);
    }
    smpb[tid] = make_float4(softplus_f(o0),
                            sigmoid_f(o1) * 1.002f - 0.001f,
                            sigmoid_f(o2) * 1.002f - 0.001f,
                            sigmoid_f(o3) * 1.002f - 0.001f);
    sdsb[tid] = sd;
    __syncthreads();

    if (tid < 4) {
        int rray = blockIdx.x * 4 + tid;
        const float4* sp  = &smpb[tid * NS];
        const float*  sdp = &sdsb[tid * NS];
        float T = 1.0f, rf = 0.f, gf = 0.f, bfv = 0.f, dep = 0.f, wsum = 0.f;
        for (int m = 0; m < NS; ++m) {
            float4 vv = sp[m];
            float sdc = sdp[m];
            float delta = (m < NS - 1) ? (sdp[m+1] - sdc) : 1e10f;
            float alpha = 1.0f - __expf(-delta * vv.x);
            float wq = alpha * T;
            rf = fmaf(wq, vv.y, rf);
            gf = fmaf(wq, vv.z, gf);
            bfv = fmaf(wq, vv.w, bfv);
            dep = fmaf(wq, sdc, dep);
            wsum += wq;
            T *= (1.0f - alpha + 1e-10f);
        }
        out[rray*3+0] = rf;
        out[rray*3+1] = gf;
        out[rray*3+2] = bfv;
        out[NRAY*3 + rray] = dep;
        out[NRAY*4 + rray] = wsum;
        out[NRAY*5 + rray] = T;
    }
}

extern "C" void kernel_launch(void* const* d_in, const int* in_sizes, int n_in,
                              void* d_out, int out_size, void* d_ws, size_t ws_size,
                              hipStream_t stream) {
    const float* planes = (const float*)d_in[0];
    const float* rayo   = (const float*)d_in[1];
    const float* rayd   = (const float*)d_in[2];
    const float* jitter = (const float*)d_in[3];
    const float* W1     = (const float*)d_in[4];
    const float* b1     = (const float*)d_in[5];
    const float* W2     = (const float*)d_in[6];
    const float* b2     = (const float*)d_in[7];
    float* out = (float*)d_out;

    const size_t pT_bytes = (size_t)BATCH * 3 * HP * HP * FEAT * 2;  // 25.2 MB bf16
    const size_t w1f_off  = pT_bytes;                 // 2048 u16 = 4 KB
    const size_t w2f_off  = w1f_off + FEAT * HID * 2; // 1024 u16 = 2 KB
    const size_t smp_off  = w2f_off + HID * 16 * 2;   // 16B-aligned
    const size_t sds_off  = smp_off + (size_t)NSAMP * 16;
    const size_t need     = sds_off + (size_t)NSAMP * 4;   // ~33 MB

    if (ws_size >= need) {
        char* ws = (char*)d_ws;
        u16*    pT  = (u16*)ws;
        u16*    W1F = (u16*)(ws + w1f_off);
        u16*    W2F = (u16*)(ws + w2f_off);
        float4* smp = (float4*)(ws + smp_off);
        float*  sds = (float*)(ws + sds_off);
        const int tgrid = BATCH * 3 * HP * HP / 256 + 1;
        hipLaunchKernelGGL(prep_kernel, dim3(tgrid), dim3(256), 0, stream,
                           planes, W1, W2, pT, W1F, W2F);
        hipLaunchKernelGGL(sample_mlp_mfma, dim3(NSAMP / 64), dim3(256), 0, stream,
                           pT, rayo, rayd, jitter, W1F, W2F, b1, b2, smp, sds);
        hipLaunchKernelGGL(composite, dim3(NRAY / 4), dim3(256), 0, stream,
                           smp, sds, out);
    } else {
        hipLaunchKernelGGL(render_fused, dim3(NRAY / 4), dim3(192), 0, stream,
                           planes, rayo, rayd, jitter, W1, b1, W2, b2, out);
    }
}

// Round 8
// 62.673 us; speedup vs baseline: 1.8855x; 1.0314x over previous
//
#include <hip/hip_runtime.h>
#include <math.h>

#define BATCH 2
#define RAYS  4096
#define NS    48
#define FEAT  32
#define HP    256
#define HID   64
#define NRAY  (BATCH*RAYS)
#define NSAMP (NRAY*NS)
#define S_DELTA (1.0f/47.0f)

typedef unsigned short u16;
typedef __attribute__((ext_vector_type(8))) short bfrag8;   // 8 bf16 (4 VGPRs)
typedef __attribute__((ext_vector_type(4))) float facc4;    // 4 f32 accum
typedef __attribute__((ext_vector_type(2))) float f32x2;    // packed f32 pair

__device__ __forceinline__ float softplus_f(float t) {
    float e = __expf(-fabsf(t));
    return fmaxf(t, 0.0f) + __logf(1.0f + e);
}
__device__ __forceinline__ float sigmoid_f(float t) {
    return 1.0f / (1.0f + __expf(-t));
}
// f32 -> bf16 round-to-nearest-even (bit trick)
__device__ __forceinline__ unsigned rtne16(float f) {
    unsigned u = __float_as_uint(f);
    return (u + 0x7FFFu + ((u >> 16) & 1u)) >> 16;
}
// packed f32 fma: d = a*b + d (full-rate on CDNA)
__device__ __forceinline__ void pk_fma(f32x2& d, f32x2 a, f32x2 b) {
    asm("v_pk_fma_f32 %0, %1, %2, %0" : "+v"(d) : "v"(a), "v"(b));
}

// ---- prep: planes f32 [bp][f][y][x] -> bf16 [bp][y][x][f]; W1,W2 -> B-frag order
__global__ __launch_bounds__(256)
void prep_kernel(const float* __restrict__ planes,
                 const float* __restrict__ W1,
                 const float* __restrict__ W2,
                 u16* __restrict__ pT,
                 u16* __restrict__ W1F,
                 u16* __restrict__ W2F) {
    int idx = blockIdx.x * 256 + threadIdx.x;
    const int total = BATCH * 3 * HP * HP;
    if (idx < total) {
        int xy = idx % (HP * HP);
        int bp = idx / (HP * HP);
        const float* src = planes + (size_t)bp * FEAT * HP * HP + xy;
        unsigned o16[16];
        #pragma unroll
        for (int k = 0; k < 16; ++k) {
            float v0 = src[(size_t)(2 * k) * HP * HP];
            float v1 = src[(size_t)(2 * k + 1) * HP * HP];
            o16[k] = rtne16(v0) | (rtne16(v1) << 16);
        }
        uint4* dst = (uint4*)(pT + (size_t)idx * FEAT);
        #pragma unroll
        for (int q = 0; q < 4; ++q)
            dst[q] = make_uint4(o16[4*q], o16[4*q+1], o16[4*q+2], o16[4*q+3]);
    } else {
        int r = idx - total;              // 0..255 (one tail block)
        // W1F: B-frag of W1[32 k][64 n]; entry e=(nt*64+l)*8+i holds
        // bf16(W1[k=(l>>4)*8+i][n=nt*16+(l&15)])
        #pragma unroll
        for (int i = 0; i < 8; ++i) {
            int e = r * 8 + i;            // 0..2047
            int nt = e >> 9, ll = (e >> 3) & 63, ii = e & 7;
            int k = ((ll >> 4) << 3) + ii;
            int nn = (nt << 4) + (ll & 15);
            W1F[e] = (u16)rtne16(W1[k * HID + nn]);
        }
        // W2F: B-frag of W2 padded [64 k][16 n]
        if (r < 128) {
            #pragma unroll
            for (int i = 0; i < 8; ++i) {
                int e = r * 8 + i;        // 0..1023
                int kk = e >> 9, ll = (e >> 3) & 63, ii = e & 7;
                int k = kk * 32 + ((ll >> 4) << 3) + ii;
                int nn = ll & 15;
                W2F[e] = (nn < 4) ? (u16)rtne16(W2[k * 4 + nn]) : (u16)0;
            }
        }
    }
}

// ---- gather helpers (bf16 texels, per-lane 8-feature chunk) ------------
__device__ __forceinline__ void corner_bf16(const u16* __restrict__ p,
                                            float w, f32x2 acc[4]) {
    uint4 q = *(const uint4*)p;
    unsigned uu[4] = {q.x, q.y, q.z, q.w};
    f32x2 w2 = {w, w};
    #pragma unroll
    for (int i = 0; i < 4; ++i) {
        f32x2 t;
        t.x = __uint_as_float(uu[i] << 16);
        t.y = __uint_as_float(uu[i] & 0xFFFF0000u);
        pk_fma(acc[i], t, w2);
    }
}

__device__ __forceinline__ void gather_plane_bf16(const u16* __restrict__ pb,
                                                  float gx, float gy, int fc8,
                                                  f32x2 acc[4]) {
    float px = (gx + 1.0f) * 0.5f * (float)(HP - 1);
    float py = (gy + 1.0f) * 0.5f * (float)(HP - 1);
    float fx = floorf(px), fy = floorf(py);
    float wx = px - fx, wy = py - fy;
    int x0 = (int)fx, y0 = (int)fy;
    int x1 = x0 + 1, y1 = y0 + 1;
    bool vx0 = (unsigned)x0 < HP, vx1 = (unsigned)x1 < HP;
    bool vy0 = (unsigned)y0 < HP, vy1 = (unsigned)y1 < HP;
    int cx0 = min(max(x0, 0), HP-1), cx1 = min(max(x1, 0), HP-1);
    int cy0 = min(max(y0, 0), HP-1), cy1 = min(max(y1, 0), HP-1);
    float w00 = (vx0 && vy0) ? (1.f-wx)*(1.f-wy) : 0.f;
    float w10 = (vx1 && vy0) ? wx*(1.f-wy)       : 0.f;
    float w01 = (vx0 && vy1) ? (1.f-wx)*wy       : 0.f;
    float w11 = (vx1 && vy1) ? wx*wy             : 0.f;
    corner_bf16(pb + ((size_t)(cy0*HP + cx0)*FEAT + fc8), w00, acc);
    corner_bf16(pb + ((size_t)(cy0*HP + cx1)*FEAT + fc8), w10, acc);
    corner_bf16(pb + ((size_t)(cy1*HP + cx0)*FEAT + fc8), w01, acc);
    corner_bf16(pb + ((size_t)(cy1*HP + cx1)*FEAT + fc8), w11, acc);
}

// ---- fused: gather + MFMA MLP + in-block composite ---------------------
// block = 768 threads = 12 waves = 192 samples = exactly 4 rays.
// wave w: 16 samples; lane l: sample (l&15), feats (l>>4)*8..+7 == A-frag
// of mfma_f32_16x16x32_bf16. C/D: row=4*(l>>4)+reg, col=l&15 (verified r7).
__global__ __launch_bounds__(768, 6)
void render_mfma(const u16* __restrict__ pT,
                 const float* __restrict__ rayo,
                 const float* __restrict__ rayd,
                 const float* __restrict__ jitter,
                 const u16* __restrict__ W1F,
                 const u16* __restrict__ W2F,
                 const float* __restrict__ b1,
                 const float* __restrict__ b2,
                 float* __restrict__ out) {
    __shared__ __align__(16) u16 hlds[12][1024];  // per-wave 16x64 bf16, XOR-swizzled
    __shared__ __align__(16) float4 s_smp[192];   // {dens,r,g,b} per sample
    __shared__ float s_sd[192];

    const int t = threadIdx.x;
    const int w = t >> 6;
    const int l = t & 63;
    const int c = l & 15;          // A-row / C-col (sample-in-wave)
    const int g = l >> 4;          // k-chunk / C row-group
    const int S0 = blockIdx.x * 192;
    const int ls = w * 16 + c;     // local sample for gather
    const int s  = S0 + ls;        // global sample
    const int ray = s / NS;
    const int n = s - ray * NS;
    const int b = ray >> 12;

    const float jit = jitter[s];
    const float sd = fmaf((float)n, S_DELTA, jit * S_DELTA);
    const float ox = rayo[ray*3+0], oy = rayo[ray*3+1], oz = rayo[ray*3+2];
    const float dx = rayd[ray*3+0], dy = rayd[ray*3+1], dz = rayd[ray*3+2];
    const float cxv = fmaf(sd, dx, ox);
    const float cyv = fmaf(sd, dy, oy);
    const float czv = fmaf(sd, dz, oz);

    f32x2 acc[4];
    #pragma unroll
    for (int i = 0; i < 4; ++i) acc[i] = (f32x2){0.f, 0.f};

    const int fc8 = g * 8;
    const u16* base = pT + (size_t)b * 3 * HP * HP * FEAT;
    gather_plane_bf16(base,                         cxv, cyv, fc8, acc);  // (x,y)
    gather_plane_bf16(base + (size_t)HP*HP*FEAT,    cxv, czv, fc8, acc);  // (x,z)
    gather_plane_bf16(base + 2*(size_t)HP*HP*FEAT,  cyv, czv, fc8, acc);  // (y,z)

    // mean over 3 planes -> bf16 A-frag
    union { unsigned u[4]; bfrag8 v; } A;
    #pragma unroll
    for (int p = 0; p < 4; ++p)
        A.u[p] = rtne16(acc[p].x * (1.f/3.f)) |
                 (rtne16(acc[p].y * (1.f/3.f)) << 16);

    // layer 1: H[16 samples][64 hid] = X @ W1   (4 MFMAs over n-tiles)
    const facc4 z4 = {0.f, 0.f, 0.f, 0.f};
    facc4 H[4];
    #pragma unroll
    for (int nt = 0; nt < 4; ++nt) {
        union { uint4 q; bfrag8 v; } B;
        B.q = *(const uint4*)(W1F + (size_t)(nt * 64 + l) * 8);
        H[nt] = __builtin_amdgcn_mfma_f32_16x16x32_bf16(A.v, B.v, z4, 0, 0, 0);
    }

    // bias + softplus -> bf16 -> LDS (XOR swizzle: byte ^= (row&7)<<4)
    char* lb = (char*)&hlds[w][0];
    #pragma unroll
    for (int nt = 0; nt < 4; ++nt) {
        const float bb = b1[nt * 16 + c];
        #pragma unroll
        for (int r = 0; r < 4; ++r) {
            const int row = g * 4 + r;                  // sample-in-wave
            const float hv = softplus_f(H[nt][r] + bb);
            const int off = row * 128 + ((((nt * 16 + c) * 2)) ^ ((row & 7) << 4));
            *(u16*)(lb + off) = (u16)rtne16(hv);
        }
    }
    // wave-private LDS: compiler inserts lgkmcnt wait; no barrier needed.

    // layer 2: O[16][4] = softplus(H) @ W2   (2 MFMAs over K=64)
    facc4 O = z4;
    #pragma unroll
    for (int kk = 0; kk < 2; ++kk) {
        union { uint4 q; bfrag8 v; } A2;
        const int off = c * 128 + ((kk * 64 + g * 16) ^ ((c & 7) << 4));
        A2.q = *(const uint4*)(lb + off);
        union { uint4 q; bfrag8 v; } B2;
        B2.q = *(const uint4*)(W2F + (size_t)(kk * 64 + l) * 8);
        O = __builtin_amdgcn_mfma_f32_16x16x32_bf16(A2.v, B2.v, O, 0, 0, 0);
    }

    // epilogue: lane holds O[sample 4g+r][col c]; cols 0..3 valid -> LDS
    if (c < 4) {
        const float bb = b2[c];
        #pragma unroll
        for (int r = 0; r < 4; ++r) {
            const int li = w * 16 + g * 4 + r;
            const float o = O[r] + bb;
            const float val = (c == 0) ? softplus_f(o)
                                       : (sigmoid_f(o) * 1.002f - 0.001f);
            ((float*)&s_smp[li])[c] = val;
        }
    }
    if (g == 0) s_sd[ls] = sd;
    __syncthreads();

    // composite: waves 0-3 each own one ray (48 samples) via prefix scan
    if (w < 4) {
        const int rray = blockIdx.x * 4 + w;
        const bool valid = l < NS;
        float4 v = make_float4(0.f, 0.f, 0.f, 0.f);
        float sdc = 0.f;
        if (valid) { v = s_smp[w * NS + l]; sdc = s_sd[w * NS + l]; }
        float sdn = __shfl_down(sdc, 1);

        float alpha = 0.f, lg = 0.f;
        if (valid) {
            float delta = (l < NS - 1) ? (sdn - sdc) : 1e10f;
            float tt = __expf(-delta * v.x);
            alpha = 1.0f - tt;
            lg = __logf(tt + 1e-10f);
        }
        float sacc = lg;
        #pragma unroll
        for (int off = 1; off < 64; off <<= 1) {
            float u = __shfl_up(sacc, off);
            if (l >= off) sacc += u;
        }
        float finalLog = __shfl(sacc, NS - 1);
        float T   = __expf(sacc - lg);
        float wgt = valid ? alpha * T : 0.f;

        float rf = wgt * v.y, gf = wgt * v.z, bf = wgt * v.w;
        float dep = wgt * sdc, wsum = wgt;
        #pragma unroll
        for (int off = 32; off; off >>= 1) {
            rf   += __shfl_xor(rf, off);
            gf   += __shfl_xor(gf, off);
            bf   += __shfl_xor(bf, off);
            dep  += __shfl_xor(dep, off);
            wsum += __shfl_xor(wsum, off);
        }
        if (l == 0) {
            out[rray * 3 + 0] = rf;
            out[rray * 3 + 1] = gf;
            out[rray * 3 + 2] = bf;
            out[NRAY * 3 + rray] = dep;
            out[NRAY * 4 + rray] = wsum;
            out[NRAY * 5 + rray] = __expf(finalLog);
        }
    }
}

// ---- fallback: fully fused fp32, direct plane layout -------------------
__global__ __launch_bounds__(192)
void render_fused(const float* __restrict__ pl,
                  const float* __restrict__ rayo,
                  const float* __restrict__ rayd,
                  const float* __restrict__ jitter,
                  const float* __restrict__ W1, const float* __restrict__ b1,
                  const float* __restrict__ W2, const float* __restrict__ b2,
                  float* __restrict__ out) {
    __shared__ float4 smpb[192];
    __shared__ float  sdsb[192];
    int tid = threadIdx.x;
    int lr  = tid / NS;
    int n   = tid - lr * NS;
    int ray = blockIdx.x * 4 + lr;
    int b   = ray >> 12;

    float jit = jitter[ray * NS + n];
    float sd  = (float)n * S_DELTA + jit * S_DELTA;
    float ox = rayo[ray*3+0], oy = rayo[ray*3+1], oz = rayo[ray*3+2];
    float dx = rayd[ray*3+0], dy = rayd[ray*3+1], dz = rayd[ray*3+2];
    float cx = fmaf(sd, dx, ox), cy = fmaf(sd, dy, oy), cz = fmaf(sd, dz, oz);

    float xv[32];
    #pragma unroll
    for (int i = 0; i < 32; ++i) xv[i] = 0.f;
    const size_t psz = (size_t)HP * HP * FEAT;
    const float* base = pl + (size_t)b * 3 * psz;
    float gxs[3] = {cx, cx, cy}, gys[3] = {cy, cz, cz};
    for (int p = 0; p < 3; ++p) {
        float px = (gxs[p] + 1.0f) * 0.5f * (float)(HP - 1);
        float py = (gys[p] + 1.0f) * 0.5f * (float)(HP - 1);
        float fx = floorf(px), fy = floorf(py);
        float wx = px - fx, wy = py - fy;
        int x0 = (int)fx, y0 = (int)fy, x1 = x0 + 1, y1 = y0 + 1;
        const float* pb = base + p * psz;
        float ws[4] = {(1.f-wx)*(1.f-wy), wx*(1.f-wy), (1.f-wx)*wy, wx*wy};
        int xs[4] = {x0, x1, x0, x1}, ys[4] = {y0, y0, y1, y1};
        for (int q = 0; q < 4; ++q) {
            if ((unsigned)xs[q] < HP && (unsigned)ys[q] < HP) {
                const float* pp = pb + (size_t)ys[q] * HP + xs[q];
                #pragma unroll
                for (int f = 0; f < 32; ++f)
                    xv[f] = fmaf(ws[q], pp[(size_t)f * HP * HP], xv[f]);
            }
        }
    }
    #pragma unroll
    for (int i = 0; i < 32; ++i) xv[i] *= (1.f/3.f);

    float o0 = b2[0], o1 = b2[1], o2 = b2[2], o3 = b2[3];
    #pragma unroll
    for (int j = 0; j < HID; ++j) {
        float hj = b1[j];
        #pragma unroll
        for (int f = 0; f < FEAT; ++f) hj = fmaf(xv[f], W1[f * HID + j], hj);
        hj = softplus_f(hj);
        o0 = fmaf(hj, W2[j*4+0], o0);
        o1 = fmaf(hj, W2[j*4+1], o1);
        o2 = fmaf(hj, W2[j*4+2], o2);
        o3 = fmaf(hj, W2[j*4+3], o3);
    }
    smpb[tid] = make_float4(softplus_f(o0),
                            sigmoid_f(o1) * 1.002f - 0.001f,
                            sigmoid_f(o2) * 1.002f - 0.001f,
                            sigmoid_f(o3) * 1.002f - 0.001f);
    sdsb[tid] = sd;
    __syncthreads();

    if (tid < 4) {
        int rray = blockIdx.x * 4 + tid;
        const float4* sp  = &smpb[tid * NS];
        const float*  sdp = &sdsb[tid * NS];
        float T = 1.0f, rf = 0.f, gf = 0.f, bfv = 0.f, dep = 0.f, wsum = 0.f;
        for (int m = 0; m < NS; ++m) {
            float4 vv = sp[m];
            float sdc = sdp[m];
            float delta = (m < NS - 1) ? (sdp[m+1] - sdc) : 1e10f;
            float alpha = 1.0f - __expf(-delta * vv.x);
            float wq = alpha * T;
            rf = fmaf(wq, vv.y, rf);
            gf = fmaf(wq, vv.z, gf);
            bfv = fmaf(wq, vv.w, bfv);
            dep = fmaf(wq, sdc, dep);
            wsum += wq;
            T *= (1.0f - alpha + 1e-10f);
        }
        out[rray*3+0] = rf;
        out[rray*3+1] = gf;
        out[rray*3+2] = bfv;
        out[NRAY*3 + rray] = dep;
        out[NRAY*4 + rray] = wsum;
        out[NRAY*5 + rray] = T;
    }
}

extern "C" void kernel_launch(void* const* d_in, const int* in_sizes, int n_in,
                              void* d_out, int out_size, void* d_ws, size_t ws_size,
                              hipStream_t stream) {
    const float* planes = (const float*)d_in[0];
    const float* rayo   = (const float*)d_in[1];
    const float* rayd   = (const float*)d_in[2];
    const float* jitter = (const float*)d_in[3];
    const float* W1     = (const float*)d_in[4];
    const float* b1     = (const float*)d_in[5];
    const float* W2     = (const float*)d_in[6];
    const float* b2     = (const float*)d_in[7];
    float* out = (float*)d_out;

    const size_t pT_bytes = (size_t)BATCH * 3 * HP * HP * FEAT * 2;  // 25.2 MB bf16
    const size_t w1f_off  = pT_bytes;
    const size_t w2f_off  = w1f_off + (size_t)FEAT * HID * 2;  // 4 KB
    const size_t need     = w2f_off + (size_t)HID * 16 * 2;    // +2 KB

    if (ws_size >= need) {
        char* ws = (char*)d_ws;
        u16* pT  = (u16*)ws;
        u16* W1F = (u16*)(ws + w1f_off);
        u16* W2F = (u16*)(ws + w2f_off);
        const int tgrid = BATCH * 3 * HP * HP / 256 + 1;
        hipLaunchKernelGGL(prep_kernel, dim3(tgrid), dim3(256), 0, stream,
                           planes, W1, W2, pT, W1F, W2F);
        hipLaunchKernelGGL(render_mfma, dim3(NSAMP / 192), dim3(768), 0, stream,
                           pT, rayo, rayd, jitter, W1F, W2F, b1, b2, out);
    } else {
        hipLaunchKernelGGL(render_fused, dim3(NRAY / 4), dim3(192), 0, stream,
                           planes, rayo, rayd, jitter, W1, b1, W2, b2, out);
    }
}

// Round 9
// 60.106 us; speedup vs baseline: 1.9660x; 1.0427x over previous
//
#include <hip/hip_runtime.h>
#include <hip/hip_fp16.h>
#include <math.h>

#define BATCH 2
#define RAYS  4096
#define NS    48
#define FEAT  32
#define HP    256
#define HID   64
#define NRAY  (BATCH*RAYS)
#define NSAMP (NRAY*NS)
#define S_DELTA (1.0f/47.0f)

typedef unsigned short u16;
typedef __attribute__((ext_vector_type(8))) _Float16 half8;  // 8 f16 (4 VGPRs)
typedef __attribute__((ext_vector_type(4))) float facc4;     // 4 f32 accum

__device__ __forceinline__ float softplus_f(float t) {
    float e = __expf(-fabsf(t));
    return fmaxf(t, 0.0f) + __logf(1.0f + e);
}
__device__ __forceinline__ float sigmoid_f(float t) {
    return 1.0f / (1.0f + __expf(-t));
}

// ---- prep: planes f32 [bp][f][y][x] -> f16 [bp][y][x][f]; W1/3,W2 -> f16 B-frags
__global__ __launch_bounds__(256)
void prep_kernel(const float* __restrict__ planes,
                 const float* __restrict__ W1,
                 const float* __restrict__ W2,
                 u16* __restrict__ pT,
                 u16* __restrict__ W1F,
                 u16* __restrict__ W2F) {
    int idx = blockIdx.x * 256 + threadIdx.x;
    const int total = BATCH * 3 * HP * HP;
    if (idx < total) {
        int xy = idx % (HP * HP);
        int bp = idx / (HP * HP);
        const float* src = planes + (size_t)bp * FEAT * HP * HP + xy;
        unsigned o16[16];
        #pragma unroll
        for (int k = 0; k < 16; ++k) {
            unsigned lo = __half_as_ushort(__float2half_rn(src[(size_t)(2*k)   * HP*HP]));
            unsigned hi = __half_as_ushort(__float2half_rn(src[(size_t)(2*k+1) * HP*HP]));
            o16[k] = lo | (hi << 16);
        }
        uint4* dst = (uint4*)(pT + (size_t)idx * FEAT);
        #pragma unroll
        for (int q = 0; q < 4; ++q)
            dst[q] = make_uint4(o16[4*q], o16[4*q+1], o16[4*q+2], o16[4*q+3]);
    } else {
        int r = idx - total;              // 0..255 (one tail block)
        // W1F: B-frag of (W1/3)[32 k][64 n]; e=(nt*64+l)*8+i holds
        // f16(W1[k=(l>>4)*8+i][n=nt*16+(l&15)] / 3)
        #pragma unroll
        for (int i = 0; i < 8; ++i) {
            int e = r * 8 + i;            // 0..2047
            int nt = e >> 9, ll = (e >> 3) & 63, ii = e & 7;
            int k = ((ll >> 4) << 3) + ii;
            int nn = (nt << 4) + (ll & 15);
            W1F[e] = __half_as_ushort(__float2half_rn(W1[k * HID + nn] * (1.f/3.f)));
        }
        // W2F: B-frag of W2 padded [64 k][16 n]
        if (r < 128) {
            #pragma unroll
            for (int i = 0; i < 8; ++i) {
                int e = r * 8 + i;        // 0..1023
                int kk = e >> 9, ll = (e >> 3) & 63, ii = e & 7;
                int k = kk * 32 + ((ll >> 4) << 3) + ii;
                int nn = ll & 15;
                W2F[e] = (nn < 4) ? __half_as_ushort(__float2half_rn(W2[k * 4 + nn]))
                                  : (u16)0;
            }
        }
    }
}

// ---- gather helpers (f16 texels; 4 x v_pk_fma_f16 per corner) ----------
__device__ __forceinline__ void corner_f16(const u16* __restrict__ p,
                                           float w, __half2 acc[4]) {
    union { uint4 q; __half2 h[4]; } U;
    U.q = *(const uint4*)p;
    __half2 w2 = __float2half2_rn(w);
    #pragma unroll
    for (int i = 0; i < 4; ++i)
        acc[i] = __hfma2(U.h[i], w2, acc[i]);
}

__device__ __forceinline__ void gather_plane_f16(const u16* __restrict__ pb,
                                                 float gx, float gy, int fc8,
                                                 __half2 acc[4]) {
    float px = (gx + 1.0f) * 0.5f * (float)(HP - 1);
    float py = (gy + 1.0f) * 0.5f * (float)(HP - 1);
    float fx = floorf(px), fy = floorf(py);
    float wx = px - fx, wy = py - fy;
    int x0 = (int)fx, y0 = (int)fy;
    int x1 = x0 + 1, y1 = y0 + 1;
    bool vx0 = (unsigned)x0 < HP, vx1 = (unsigned)x1 < HP;
    bool vy0 = (unsigned)y0 < HP, vy1 = (unsigned)y1 < HP;
    int cx0 = min(max(x0, 0), HP-1), cx1 = min(max(x1, 0), HP-1);
    int cy0 = min(max(y0, 0), HP-1), cy1 = min(max(y1, 0), HP-1);
    float w00 = (vx0 && vy0) ? (1.f-wx)*(1.f-wy) : 0.f;
    float w10 = (vx1 && vy0) ? wx*(1.f-wy)       : 0.f;
    float w01 = (vx0 && vy1) ? (1.f-wx)*wy       : 0.f;
    float w11 = (vx1 && vy1) ? wx*wy             : 0.f;
    corner_f16(pb + ((size_t)(cy0*HP + cx0)*FEAT + fc8), w00, acc);
    corner_f16(pb + ((size_t)(cy0*HP + cx1)*FEAT + fc8), w10, acc);
    corner_f16(pb + ((size_t)(cy1*HP + cx0)*FEAT + fc8), w01, acc);
    corner_f16(pb + ((size_t)(cy1*HP + cx1)*FEAT + fc8), w11, acc);
}

// ---- fused: gather + f16 MFMA MLP + in-block composite -----------------
// block = 768 threads = 12 waves = 192 samples = exactly 4 rays.
// wave w: 16 samples; lane l: sample (l&15), feats (l>>4)*8..+7 == A-frag
// of mfma_f32_16x16x32_f16 (same geometry as bf16; layout dtype-independent).
// C/D: row=4*(l>>4)+reg, col=l&15 (verified r7 on HW).
__global__ __launch_bounds__(768, 6)
void render_mfma(const u16* __restrict__ pT,
                 const float* __restrict__ rayo,
                 const float* __restrict__ rayd,
                 const float* __restrict__ jitter,
                 const u16* __restrict__ W1F,
                 const u16* __restrict__ W2F,
                 const float* __restrict__ b1,
                 const float* __restrict__ b2,
                 float* __restrict__ out) {
    __shared__ __align__(16) u16 hlds[12][1024];  // per-wave 16x64 f16, XOR-swizzled
    __shared__ __align__(16) float4 s_smp[192];   // {dens,r,g,b} per sample
    __shared__ float s_sd[192];

    const int t = threadIdx.x;
    const int w = t >> 6;
    const int l = t & 63;
    const int c = l & 15;          // A-row / C-col (sample-in-wave)
    const int g = l >> 4;          // k-chunk / C row-group
    const int S0 = blockIdx.x * 192;
    const int ls = w * 16 + c;     // local sample
    const int s  = S0 + ls;        // global sample
    const int ray = s / NS;
    const int n = s - ray * NS;
    const int b = ray >> 12;

    const float jit = jitter[s];
    const float sd = fmaf((float)n, S_DELTA, jit * S_DELTA);
    const float ox = rayo[ray*3+0], oy = rayo[ray*3+1], oz = rayo[ray*3+2];
    const float dx = rayd[ray*3+0], dy = rayd[ray*3+1], dz = rayd[ray*3+2];
    const float cxv = fmaf(sd, dx, ox);
    const float cyv = fmaf(sd, dy, oy);
    const float czv = fmaf(sd, dz, oz);

    __half2 acc[4];
    #pragma unroll
    for (int i = 0; i < 4; ++i) acc[i] = __float2half2_rn(0.f);

    const int fc8 = g * 8;
    const u16* base = pT + (size_t)b * 3 * HP * HP * FEAT;
    gather_plane_f16(base,                         cxv, cyv, fc8, acc);  // (x,y)
    gather_plane_f16(base + (size_t)HP*HP*FEAT,    cxv, czv, fc8, acc);  // (x,z)
    gather_plane_f16(base + 2*(size_t)HP*HP*FEAT,  cyv, czv, fc8, acc);  // (y,z)

    // acc IS the A-frag (sum over planes; 1/3 folded into W1F)
    union { __half2 h[4]; half8 v; } A;
    #pragma unroll
    for (int i = 0; i < 4; ++i) A.h[i] = acc[i];

    // layer 1: H[16 samples][64 hid] = (3x) @ (W1/3)   (4 MFMAs over n-tiles)
    const facc4 z4 = {0.f, 0.f, 0.f, 0.f};
    facc4 H[4];
    #pragma unroll
    for (int nt = 0; nt < 4; ++nt) {
        union { uint4 q; half8 v; } B;
        B.q = *(const uint4*)(W1F + (size_t)(nt * 64 + l) * 8);
        H[nt] = __builtin_amdgcn_mfma_f32_16x16x32_f16(A.v, B.v, z4, 0, 0, 0);
    }

    // bias + softplus -> f16 -> LDS (XOR swizzle: byte ^= (row&7)<<4)
    char* lb = (char*)&hlds[w][0];
    #pragma unroll
    for (int nt = 0; nt < 4; ++nt) {
        const float bb = b1[nt * 16 + c];
        #pragma unroll
        for (int r = 0; r < 4; ++r) {
            const int row = g * 4 + r;                  // sample-in-wave
            const float hv = softplus_f(H[nt][r] + bb);
            const int off = row * 128 + ((((nt * 16 + c) * 2)) ^ ((row & 7) << 4));
            *(u16*)(lb + off) = __half_as_ushort(__float2half_rn(hv));
        }
    }
    // wave-private LDS: compiler inserts lgkmcnt wait; no barrier needed.

    // layer 2: O[16][4] = softplus(H) @ W2   (2 MFMAs over K=64)
    facc4 O = z4;
    #pragma unroll
    for (int kk = 0; kk < 2; ++kk) {
        union { uint4 q; half8 v; } A2;
        const int off = c * 128 + ((kk * 64 + g * 16) ^ ((c & 7) << 4));
        A2.q = *(const uint4*)(lb + off);
        union { uint4 q; half8 v; } B2;
        B2.q = *(const uint4*)(W2F + (size_t)(kk * 64 + l) * 8);
        O = __builtin_amdgcn_mfma_f32_16x16x32_f16(A2.v, B2.v, O, 0, 0, 0);
    }

    // epilogue: lane holds O[sample 4g+r][col c]; cols 0..3 valid -> LDS
    if (c < 4) {
        const float bb = b2[c];
        #pragma unroll
        for (int r = 0; r < 4; ++r) {
            const int li = w * 16 + g * 4 + r;
            const float o = O[r] + bb;
            const float val = (c == 0) ? softplus_f(o)
                                       : (sigmoid_f(o) * 1.002f - 0.001f);
            ((float*)&s_smp[li])[c] = val;
        }
    }
    if (g == 0) s_sd[ls] = sd;
    __syncthreads();

    // composite: waves 0-3 each own one ray (48 samples) via prefix scan
    if (w < 4) {
        const int rray = blockIdx.x * 4 + w;
        const bool valid = l < NS;
        float4 v = make_float4(0.f, 0.f, 0.f, 0.f);
        float sdc = 0.f;
        if (valid) { v = s_smp[w * NS + l]; sdc = s_sd[w * NS + l]; }
        float sdn = __shfl_down(sdc, 1);

        float alpha = 0.f, lg = 0.f;
        if (valid) {
            float delta = (l < NS - 1) ? (sdn - sdc) : 1e10f;
            float tt = __expf(-delta * v.x);
            alpha = 1.0f - tt;
            lg = __logf(tt + 1e-10f);
        }
        float sacc = lg;
        #pragma unroll
        for (int off = 1; off < 64; off <<= 1) {
            float u = __shfl_up(sacc, off);
            if (l >= off) sacc += u;
        }
        float finalLog = __shfl(sacc, NS - 1);
        float T   = __expf(sacc - lg);
        float wgt = valid ? alpha * T : 0.f;

        float rf = wgt * v.y, gf = wgt * v.z, bf = wgt * v.w;
        float dep = wgt * sdc, wsum = wgt;
        #pragma unroll
        for (int off = 32; off; off >>= 1) {
            rf   += __shfl_xor(rf, off);
            gf   += __shfl_xor(gf, off);
            bf   += __shfl_xor(bf, off);
            dep  += __shfl_xor(dep, off);
            wsum += __shfl_xor(wsum, off);
        }
        if (l == 0) {
            out[rray * 3 + 0] = rf;
            out[rray * 3 + 1] = gf;
            out[rray * 3 + 2] = bf;
            out[NRAY * 3 + rray] = dep;
            out[NRAY * 4 + rray] = wsum;
            out[NRAY * 5 + rray] = __expf(finalLog);
        }
    }
}

// ---- fallback: fully fused fp32, direct plane layout -------------------
__global__ __launch_bounds__(192)
void render_fused(const float* __restrict__ pl,
                  const float* __restrict__ rayo,
                  const float* __restrict__ rayd,
                  const float* __restrict__ jitter,
                  const float* __restrict__ W1, const float* __restrict__ b1,
                  const float* __restrict__ W2, const float* __restrict__ b2,
                  float* __restrict__ out) {
    __shared__ float4 smpb[192];
    __shared__ float  sdsb[192];
    int tid = threadIdx.x;
    int lr  = tid / NS;
    int n   = tid - lr * NS;
    int ray = blockIdx.x * 4 + lr;
    int b   = ray >> 12;

    float jit = jitter[ray * NS + n];
    float sd  = (float)n * S_DELTA + jit * S_DELTA;
    float ox = rayo[ray*3+0], oy = rayo[ray*3+1], oz = rayo[ray*3+2];
    float dx = rayd[ray*3+0], dy = rayd[ray*3+1], dz = rayd[ray*3+2];
    float cx = fmaf(sd, dx, ox), cy = fmaf(sd, dy, oy), cz = fmaf(sd, dz, oz);

    float xv[32];
    #pragma unroll
    for (int i = 0; i < 32; ++i) xv[i] = 0.f;
    const size_t psz = (size_t)HP * HP * FEAT;
    const float* base = pl + (size_t)b * 3 * psz;
    float gxs[3] = {cx, cx, cy}, gys[3] = {cy, cz, cz};
    for (int p = 0; p < 3; ++p) {
        float px = (gxs[p] + 1.0f) * 0.5f * (float)(HP - 1);
        float py = (gys[p] + 1.0f) * 0.5f * (float)(HP - 1);
        float fx = floorf(px), fy = floorf(py);
        float wx = px - fx, wy = py - fy;
        int x0 = (int)fx, y0 = (int)fy, x1 = x0 + 1, y1 = y0 + 1;
        const float* pb = base + p * psz;
        float ws[4] = {(1.f-wx)*(1.f-wy), wx*(1.f-wy), (1.f-wx)*wy, wx*wy};
        int xs[4] = {x0, x1, x0, x1}, ys[4] = {y0, y0, y1, y1};
        for (int q = 0; q < 4; ++q) {
            if ((unsigned)xs[q] < HP && (unsigned)ys[q] < HP) {
                const float* pp = pb + (size_t)ys[q] * HP + xs[q];
                #pragma unroll
                for (int f = 0; f < 32; ++f)
                    xv[f] = fmaf(ws[q], pp[(size_t)f * HP * HP], xv[f]);
            }
        }
    }
    #pragma unroll
    for (int i = 0; i < 32; ++i) xv[i] *= (1.f/3.f);

    float o0 = b2[0], o1 = b2[1], o2 = b2[2], o3 = b2[3];
    #pragma unroll
    for (int j = 0; j < HID; ++j) {
        float hj = b1[j];
        #pragma unroll
        for (int f = 0; f < FEAT; ++f) hj = fmaf(xv[f], W1[f * HID + j], hj);
        hj = softplus_f(hj);
        o0 = fmaf(hj, W2[j*4+0], o0);
        o1 = fmaf(hj, W2[j*4+1], o1);
        o2 = fmaf(hj, W2[j*4+2], o2);
        o3 = fmaf(hj, W2[j*4+3], o3);
    }
    smpb[tid] = make_float4(softplus_f(o0),
                            sigmoid_f(o1) * 1.002f - 0.001f,
                            sigmoid_f(o2) * 1.002f - 0.001f,
                            sigmoid_f(o3) * 1.002f - 0.001f);
    sdsb[tid] = sd;
    __syncthreads();

    if (tid < 4) {
        int rray = blockIdx.x * 4 + tid;
        const float4* sp  = &smpb[tid * NS];
        const float*  sdp = &sdsb[tid * NS];
        float T = 1.0f, rf = 0.f, gf = 0.f, bfv = 0.f, dep = 0.f, wsum = 0.f;
        for (int m = 0; m < NS; ++m) {
            float4 vv = sp[m];
            float sdc = sdp[m];
            float delta = (m < NS - 1) ? (sdp[m+1] - sdc) : 1e10f;
            float alpha = 1.0f - __expf(-delta * vv.x);
            float wq = alpha * T;
            rf = fmaf(wq, vv.y, rf);
            gf = fmaf(wq, vv.z, gf);
            bfv = fmaf(wq, vv.w, bfv);
            dep = fmaf(wq, sdc, dep);
            wsum += wq;
            T *= (1.0f - alpha + 1e-10f);
        }
        out[rray*3+0] = rf;
        out[rray*3+1] = gf;
        out[rray*3+2] = bfv;
        out[NRAY*3 + rray] = dep;
        out[NRAY*4 + rray] = wsum;
        out[NRAY*5 + rray] = T;
    }
}

extern "C" void kernel_launch(void* const* d_in, const int* in_sizes, int n_in,
                              void* d_out, int out_size, void* d_ws, size_t ws_size,
                              hipStream_t stream) {
    const float* planes = (const float*)d_in[0];
    const float* rayo   = (const float*)d_in[1];
    const float* rayd   = (const float*)d_in[2];
    const float* jitter = (const float*)d_in[3];
    const float* W1     = (const float*)d_in[4];
    const float* b1     = (const float*)d_in[5];
    const float* W2     = (const float*)d_in[6];
    const float* b2     = (const float*)d_in[7];
    float* out = (float*)d_out;

    const size_t pT_bytes = (size_t)BATCH * 3 * HP * HP * FEAT * 2;  // 25.2 MB f16
    const size_t w1f_off  = pT_bytes;
    const size_t w2f_off  = w1f_off + (size_t)FEAT * HID * 2;  // 4 KB
    const size_t need     = w2f_off + (size_t)HID * 16 * 2;    // +2 KB

    if (ws_size >= need) {
        char* ws = (char*)d_ws;
        u16* pT  = (u16*)ws;
        u16* W1F = (u16*)(ws + w1f_off);
        u16* W2F = (u16*)(ws + w2f_off);
        const int tgrid = BATCH * 3 * HP * HP / 256 + 1;
        hipLaunchKernelGGL(prep_kernel, dim3(tgrid), dim3(256), 0, stream,
                           planes, W1, W2, pT, W1F, W2F);
        hipLaunchKernelGGL(render_mfma, dim3(NSAMP / 192), dim3(768), 0, stream,
                           pT, rayo, rayd, jitter, W1F, W2F, b1, b2, out);
    } else {
        hipLaunchKernelGGL(render_fused, dim3(NRAY / 4), dim3(192), 0, stream,
                           planes, rayo, rayd, jitter, W1, b1, W2, b2, out);
    }
}

// Round 10
// 58.466 us; speedup vs baseline: 2.0211x; 1.0281x over previous
//
#include <hip/hip_runtime.h>
#include <hip/hip_fp16.h>
#include <math.h>

#define BATCH 2
#define RAYS  4096
#define NS    48
#define FEAT  32
#define HP    256
#define HID   64
#define NRAY  (BATCH*RAYS)
#define NSAMP (NRAY*NS)
#define S_DELTA (1.0f/47.0f)

typedef unsigned short u16;
typedef __attribute__((ext_vector_type(8))) _Float16 half8;  // 8 f16 (4 VGPRs)
typedef __attribute__((ext_vector_type(4))) float facc4;     // 4 f32 accum

__device__ __forceinline__ float softplus_f(float t) {
    float e = __expf(-fabsf(t));
    return fmaxf(t, 0.0f) + __logf(1.0f + e);
}
__device__ __forceinline__ float sigmoid_f(float t) {
    return 1.0f / (1.0f + __expf(-t));
}

// ---- prep: planes f32 [bp][f][y][x] -> f16 [bp][y][x][f]; W1/3,W2 -> f16 B-frags
__global__ __launch_bounds__(256)
void prep_kernel(const float* __restrict__ planes,
                 const float* __restrict__ W1,
                 const float* __restrict__ W2,
                 u16* __restrict__ pT,
                 u16* __restrict__ W1F,
                 u16* __restrict__ W2F) {
    int idx = blockIdx.x * 256 + threadIdx.x;
    const int total = BATCH * 3 * HP * HP;
    if (idx < total) {
        int xy = idx % (HP * HP);
        int bp = idx / (HP * HP);
        const float* src = planes + (size_t)bp * FEAT * HP * HP + xy;
        unsigned o16[16];
        #pragma unroll
        for (int k = 0; k < 16; ++k) {
            unsigned lo = __half_as_ushort(__float2half_rn(src[(size_t)(2*k)   * HP*HP]));
            unsigned hi = __half_as_ushort(__float2half_rn(src[(size_t)(2*k+1) * HP*HP]));
            o16[k] = lo | (hi << 16);
        }
        uint4* dst = (uint4*)(pT + (size_t)idx * FEAT);
        #pragma unroll
        for (int q = 0; q < 4; ++q)
            dst[q] = make_uint4(o16[4*q], o16[4*q+1], o16[4*q+2], o16[4*q+3]);
    } else {
        int r = idx - total;              // 0..255 (one tail block)
        // W1F: B-frag of (W1/3)[32 k][64 n]; e=(nt*64+l)*8+i holds
        // f16(W1[k=(l>>4)*8+i][n=nt*16+(l&15)] / 3)
        #pragma unroll
        for (int i = 0; i < 8; ++i) {
            int e = r * 8 + i;            // 0..2047
            int nt = e >> 9, ll = (e >> 3) & 63, ii = e & 7;
            int k = ((ll >> 4) << 3) + ii;
            int nn = (nt << 4) + (ll & 15);
            W1F[e] = __half_as_ushort(__float2half_rn(W1[k * HID + nn] * (1.f/3.f)));
        }
        // W2F: B-frag of W2 padded [64 k][16 n]
        if (r < 128) {
            #pragma unroll
            for (int i = 0; i < 8; ++i) {
                int e = r * 8 + i;        // 0..1023
                int kk = e >> 9, ll = (e >> 3) & 63, ii = e & 7;
                int k = kk * 32 + ((ll >> 4) << 3) + ii;
                int nn = ll & 15;
                W2F[e] = (nn < 4) ? __half_as_ushort(__float2half_rn(W2[k * 4 + nn]))
                                  : (u16)0;
            }
        }
    }
}

// ---- gather helpers (f16 texels; 4 x v_pk_fma_f16 per corner) ----------
__device__ __forceinline__ void corner_f16(const u16* __restrict__ p,
                                           float w, __half2 acc[4]) {
    union { uint4 q; __half2 h[4]; } U;
    U.q = *(const uint4*)p;
    __half2 w2 = __float2half2_rn(w);
    #pragma unroll
    for (int i = 0; i < 4; ++i)
        acc[i] = __hfma2(U.h[i], w2, acc[i]);
}

__device__ __forceinline__ void gather_plane_f16(const u16* __restrict__ pb,
                                                 float gx, float gy, int fc8,
                                                 __half2 acc[4]) {
    float px = (gx + 1.0f) * 0.5f * (float)(HP - 1);
    float py = (gy + 1.0f) * 0.5f * (float)(HP - 1);
    float fx = floorf(px), fy = floorf(py);
    float wx = px - fx, wy = py - fy;
    int x0 = (int)fx, y0 = (int)fy;
    int x1 = x0 + 1, y1 = y0 + 1;
    bool vx0 = (unsigned)x0 < HP, vx1 = (unsigned)x1 < HP;
    bool vy0 = (unsigned)y0 < HP, vy1 = (unsigned)y1 < HP;
    int cx0 = min(max(x0, 0), HP-1), cx1 = min(max(x1, 0), HP-1);
    int cy0 = min(max(y0, 0), HP-1), cy1 = min(max(y1, 0), HP-1);
    float w00 = (vx0 && vy0) ? (1.f-wx)*(1.f-wy) : 0.f;
    float w10 = (vx1 && vy0) ? wx*(1.f-wy)       : 0.f;
    float w01 = (vx0 && vy1) ? (1.f-wx)*wy       : 0.f;
    float w11 = (vx1 && vy1) ? wx*wy             : 0.f;
    corner_f16(pb + ((size_t)(cy0*HP + cx0)*FEAT + fc8), w00, acc);
    corner_f16(pb + ((size_t)(cy0*HP + cx1)*FEAT + fc8), w10, acc);
    corner_f16(pb + ((size_t)(cy1*HP + cx0)*FEAT + fc8), w01, acc);
    corner_f16(pb + ((size_t)(cy1*HP + cx1)*FEAT + fc8), w11, acc);
}

// ---- fused: gather + f16 MFMA MLP + in-block composite -----------------
// block = 192 threads = 3 waves = 48 samples = EXACTLY ONE RAY.
// wave w: 16 samples; lane l: sample (l&15), feats (l>>4)*8..+7 == A-frag
// of mfma_f32_16x16x32_f16. C/D: row=4*(l>>4)+reg, col=l&15 (verified r7).
// Bias b1/b2 folded into MFMA C-init (f32 accumulator).
__global__ __launch_bounds__(192, 8)
void render_mfma(const u16* __restrict__ pT,
                 const float* __restrict__ rayo,
                 const float* __restrict__ rayd,
                 const float* __restrict__ jitter,
                 const u16* __restrict__ W1F,
                 const u16* __restrict__ W2F,
                 const float* __restrict__ b1,
                 const float* __restrict__ b2,
                 float* __restrict__ out) {
    __shared__ __align__(16) u16 hlds[3][1024];  // per-wave 16x64 f16, XOR-swizzled
    __shared__ __align__(16) float4 s_smp[48];   // {dens,r,g,b} per sample
    __shared__ float s_sd[48];

    const int t = threadIdx.x;
    const int w = t >> 6;
    const int l = t & 63;
    const int c = l & 15;          // A-row / C-col (sample-in-wave)
    const int g = l >> 4;          // k-chunk / C row-group
    const int ray = blockIdx.x;    // one ray per block
    const int ls = w * 16 + c;     // local sample == n
    const int s  = ray * NS + ls;  // global sample
    const int b  = ray >> 12;

    const float jit = jitter[s];
    const float sd = fmaf((float)ls, S_DELTA, jit * S_DELTA);
    const float ox = rayo[ray*3+0], oy = rayo[ray*3+1], oz = rayo[ray*3+2];
    const float dx = rayd[ray*3+0], dy = rayd[ray*3+1], dz = rayd[ray*3+2];
    const float cxv = fmaf(sd, dx, ox);
    const float cyv = fmaf(sd, dy, oy);
    const float czv = fmaf(sd, dz, oz);

    // 3 independent accumulator chains (ILP), summed at the end
    __half2 a0[4], a1[4], a2[4];
    #pragma unroll
    for (int i = 0; i < 4; ++i) {
        a0[i] = __float2half2_rn(0.f);
        a1[i] = __float2half2_rn(0.f);
        a2[i] = __float2half2_rn(0.f);
    }

    const int fc8 = g * 8;
    const u16* base = pT + (size_t)b * 3 * HP * HP * FEAT;
    gather_plane_f16(base,                         cxv, cyv, fc8, a0);  // (x,y)
    gather_plane_f16(base + (size_t)HP*HP*FEAT,    cxv, czv, fc8, a1);  // (x,z)
    gather_plane_f16(base + 2*(size_t)HP*HP*FEAT,  cyv, czv, fc8, a2);  // (y,z)

    // sum planes -> A-frag (1/3 folded into W1F)
    union { __half2 h[4]; half8 v; } A;
    #pragma unroll
    for (int i = 0; i < 4; ++i)
        A.h[i] = __hadd2(__hadd2(a0[i], a1[i]), a2[i]);

    // layer 1: H[16 samples][64 hid] = X @ (W1/3) + b1 (bias in C-init)
    facc4 H[4];
    #pragma unroll
    for (int nt = 0; nt < 4; ++nt) {
        const float bb = b1[nt * 16 + c];          // C col = hid = nt*16+c
        facc4 Cb = {bb, bb, bb, bb};
        union { uint4 q; half8 v; } B;
        B.q = *(const uint4*)(W1F + (size_t)(nt * 64 + l) * 8);
        H[nt] = __builtin_amdgcn_mfma_f32_16x16x32_f16(A.v, B.v, Cb, 0, 0, 0);
    }

    // softplus -> f16 -> LDS (XOR swizzle: byte ^= (row&7)<<4)
    char* lb = (char*)&hlds[w][0];
    #pragma unroll
    for (int nt = 0; nt < 4; ++nt) {
        #pragma unroll
        for (int r = 0; r < 4; ++r) {
            const int row = g * 4 + r;                  // sample-in-wave
            const float hv = softplus_f(H[nt][r]);
            const int off = row * 128 + ((((nt * 16 + c) * 2)) ^ ((row & 7) << 4));
            *(u16*)(lb + off) = __half_as_ushort(__float2half_rn(hv));
        }
    }
    // wave-private LDS: compiler inserts lgkmcnt wait; no barrier needed.

    // layer 2: O[16][4] = softplus(H) @ W2 + b2 (bias in C-init; C col = c)
    const float bb2 = b2[c & 3];
    facc4 O = {bb2, bb2, bb2, bb2};
    #pragma unroll
    for (int kk = 0; kk < 2; ++kk) {
        union { uint4 q; half8 v; } A2;
        const int off = c * 128 + ((kk * 64 + g * 16) ^ ((c & 7) << 4));
        A2.q = *(const uint4*)(lb + off);
        union { uint4 q; half8 v; } B2;
        B2.q = *(const uint4*)(W2F + (size_t)(kk * 64 + l) * 8);
        O = __builtin_amdgcn_mfma_f32_16x16x32_f16(A2.v, B2.v, O, 0, 0, 0);
    }

    // epilogue: lane holds O[sample 4g+r][col c]; cols 0..3 valid -> LDS
    if (c < 4) {
        #pragma unroll
        for (int r = 0; r < 4; ++r) {
            const int li = w * 16 + g * 4 + r;
            const float o = O[r];
            const float val = (c == 0) ? softplus_f(o)
                                       : (sigmoid_f(o) * 1.002f - 0.001f);
            ((float*)&s_smp[li])[c] = val;
        }
    }
    if (g == 0) s_sd[ls] = sd;
    __syncthreads();

    // composite: wave 0 scans this block's ray (48 samples)
    if (w == 0) {
        const bool valid = l < NS;
        float4 v = make_float4(0.f, 0.f, 0.f, 0.f);
        float sdc = 0.f;
        if (valid) { v = s_smp[l]; sdc = s_sd[l]; }
        float sdn = __shfl_down(sdc, 1);

        float alpha = 0.f, lg = 0.f;
        if (valid) {
            float delta = (l < NS - 1) ? (sdn - sdc) : 1e10f;
            float tt = __expf(-delta * v.x);
            alpha = 1.0f - tt;
            lg = __logf(tt + 1e-10f);
        }
        float sacc = lg;
        #pragma unroll
        for (int off = 1; off < 64; off <<= 1) {
            float u = __shfl_up(sacc, off);
            if (l >= off) sacc += u;
        }
        float finalLog = __shfl(sacc, NS - 1);
        float T   = __expf(sacc - lg);
        float wgt = valid ? alpha * T : 0.f;

        float rf = wgt * v.y, gf = wgt * v.z, bf = wgt * v.w;
        float dep = wgt * sdc, wsum = wgt;
        #pragma unroll
        for (int off = 32; off; off >>= 1) {
            rf   += __shfl_xor(rf, off);
            gf   += __shfl_xor(gf, off);
            bf   += __shfl_xor(bf, off);
            dep  += __shfl_xor(dep, off);
            wsum += __shfl_xor(wsum, off);
        }
        if (l == 0) {
            out[ray * 3 + 0] = rf;
            out[ray * 3 + 1] = gf;
            out[ray * 3 + 2] = bf;
            out[NRAY * 3 + ray] = dep;
            out[NRAY * 4 + ray] = wsum;
            out[NRAY * 5 + ray] = __expf(finalLog);
        }
    }
}

// ---- fallback: fully fused fp32, direct plane layout -------------------
__global__ __launch_bounds__(192)
void render_fused(const float* __restrict__ pl,
                  const float* __restrict__ rayo,
                  const float* __restrict__ rayd,
                  const float* __restrict__ jitter,
                  const float* __restrict__ W1, const float* __restrict__ b1,
                  const float* __restrict__ W2, const float* __restrict__ b2,
                  float* __restrict__ out) {
    __shared__ float4 smpb[192];
    __shared__ float  sdsb[192];
    int tid = threadIdx.x;
    int lr  = tid / NS;
    int n   = tid - lr * NS;
    int ray = blockIdx.x * 4 + lr;
    int b   = ray >> 12;

    float jit = jitter[ray * NS + n];
    float sd  = (float)n * S_DELTA + jit * S_DELTA;
    float ox = rayo[ray*3+0], oy = rayo[ray*3+1], oz = rayo[ray*3+2];
    float dx = rayd[ray*3+0], dy = rayd[ray*3+1], dz = rayd[ray*3+2];
    float cx = fmaf(sd, dx, ox), cy = fmaf(sd, dy, oy), cz = fmaf(sd, dz, oz);

    float xv[32];
    #pragma unroll
    for (int i = 0; i < 32; ++i) xv[i] = 0.f;
    const size_t psz = (size_t)HP * HP * FEAT;
    const float* base = pl + (size_t)b * 3 * psz;
    float gxs[3] = {cx, cx, cy}, gys[3] = {cy, cz, cz};
    for (int p = 0; p < 3; ++p) {
        float px = (gxs[p] + 1.0f) * 0.5f * (float)(HP - 1);
        float py = (gys[p] + 1.0f) * 0.5f * (float)(HP - 1);
        float fx = floorf(px), fy = floorf(py);
        float wx = px - fx, wy = py - fy;
        int x0 = (int)fx, y0 = (int)fy, x1 = x0 + 1, y1 = y0 + 1;
        const float* pb = base + p * psz;
        float ws[4] = {(1.f-wx)*(1.f-wy), wx*(1.f-wy), (1.f-wx)*wy, wx*wy};
        int xs[4] = {x0, x1, x0, x1}, ys[4] = {y0, y0, y1, y1};
        for (int q = 0; q < 4; ++q) {
            if ((unsigned)xs[q] < HP && (unsigned)ys[q] < HP) {
                const float* pp = pb + (size_t)ys[q] * HP + xs[q];
                #pragma unroll
                for (int f = 0; f < 32; ++f)
                    xv[f] = fmaf(ws[q], pp[(size_t)f * HP * HP], xv[f]);
            }
        }
    }
    #pragma unroll
    for (int i = 0; i < 32; ++i) xv[i] *= (1.f/3.f);

    float o0 = b2[0], o1 = b2[1], o2 = b2[2], o3 = b2[3];
    #pragma unroll
    for (int j = 0; j < HID; ++j) {
        float hj = b1[j];
        #pragma unroll
        for (int f = 0; f < FEAT; ++f) hj = fmaf(xv[f], W1[f * HID + j], hj);
        hj = softplus_f(hj);
        o0 = fmaf(hj, W2[j*4+0], o0);
        o1 = fmaf(hj, W2[j*4+1], o1);
        o2 = fmaf(hj, W2[j*4+2], o2);
        o3 = fmaf(hj, W2[j*4+3], o3);
    }
    smpb[tid] = make_float4(softplus_f(o0),
                            sigmoid_f(o1) * 1.002f - 0.001f,
                            sigmoid_f(o2) * 1.002f - 0.001f,
                            sigmoid_f(o3) * 1.002f - 0.001f);
    sdsb[tid] = sd;
    __syncthreads();

    if (tid < 4) {
        int rray = blockIdx.x * 4 + tid;
        const float4* sp  = &smpb[tid * NS];
        const float*  sdp = &sdsb[tid * NS];
        float T = 1.0f, rf = 0.f, gf = 0.f, bfv = 0.f, dep = 0.f, wsum = 0.f;
        for (int m = 0; m < NS; ++m) {
            float4 vv = sp[m];
            float sdc = sdp[m];
            float delta = (m < NS - 1) ? (sdp[m+1] - sdc) : 1e10f;
            float alpha = 1.0f - __expf(-delta * vv.x);
            float wq = alpha * T;
            rf = fmaf(wq, vv.y, rf);
            gf = fmaf(wq, vv.z, gf);
            bfv = fmaf(wq, vv.w, bfv);
            dep = fmaf(wq, sdc, dep);
            wsum += wq;
            T *= (1.0f - alpha + 1e-10f);
        }
        out[rray*3+0] = rf;
        out[rray*3+1] = gf;
        out[rray*3+2] = bfv;
        out[NRAY*3 + rray] = dep;
        out[NRAY*4 + rray] = wsum;
        out[NRAY*5 + rray] = T;
    }
}

extern "C" void kernel_launch(void* const* d_in, const int* in_sizes, int n_in,
                              void* d_out, int out_size, void* d_ws, size_t ws_size,
                              hipStream_t stream) {
    const float* planes = (const float*)d_in[0];
    const float* rayo   = (const float*)d_in[1];
    const float* rayd   = (const float*)d_in[2];
    const float* jitter = (const float*)d_in[3];
    const float* W1     = (const float*)d_in[4];
    const float* b1     = (const float*)d_in[5];
    const float* W2     = (const float*)d_in[6];
    const float* b2     = (const float*)d_in[7];
    float* out = (float*)d_out;

    const size_t pT_bytes = (size_t)BATCH * 3 * HP * HP * FEAT * 2;  // 25.2 MB f16
    const size_t w1f_off  = pT_bytes;
    const size_t w2f_off  = w1f_off + (size_t)FEAT * HID * 2;  // 4 KB
    const size_t need     = w2f_off + (size_t)HID * 16 * 2;    // +2 KB

    if (ws_size >= need) {
        char* ws = (char*)d_ws;
        u16* pT  = (u16*)ws;
        u16* W1F = (u16*)(ws + w1f_off);
        u16* W2F = (u16*)(ws + w2f_off);
        const int tgrid = BATCH * 3 * HP * HP / 256 + 1;
        hipLaunchKernelGGL(prep_kernel, dim3(tgrid), dim3(256), 0, stream,
                           planes, W1, W2, pT, W1F, W2F);
        hipLaunchKernelGGL(render_mfma, dim3(NRAY), dim3(192), 0, stream,
                           pT, rayo, rayd, jitter, W1F, W2F, b1, b2, out);
    } else {
        hipLaunchKernelGGL(render_fused, dim3(NRAY / 4), dim3(192), 0, stream,
                           planes, rayo, rayd, jitter, W1, b1, W2, b2, out);
    }
}

// Round 11
// 58.041 us; speedup vs baseline: 2.0359x; 1.0073x over previous
//
#include <hip/hip_runtime.h>
#include <hip/hip_fp16.h>
#include <math.h>

#define BATCH 2
#define RAYS  4096
#define NS    48
#define FEAT  32
#define HP    256
#define HID   64
#define NRAY  (BATCH*RAYS)
#define NSAMP (NRAY*NS)
#define S_DELTA (1.0f/47.0f)
#define PSZ   (HP*HP*FEAT)          // elements per plane

typedef unsigned short u16;
typedef __attribute__((ext_vector_type(8))) _Float16 half8;  // 8 f16 (4 VGPRs)
typedef __attribute__((ext_vector_type(4))) float facc4;     // 4 f32 accum

__device__ __forceinline__ float softplus_f(float t) {
    float e = __expf(-fabsf(t));
    return fmaxf(t, 0.0f) + __logf(1.0f + e);
}
__device__ __forceinline__ float sigmoid_f(float t) {
    return 1.0f / (1.0f + __expf(-t));
}

// ---- prep: planes f32 [bp][f][y][x] -> f16 [bp][y][x][f]; W1/3,W2 -> f16 B-frags
__global__ __launch_bounds__(256)
void prep_kernel(const float* __restrict__ planes,
                 const float* __restrict__ W1,
                 const float* __restrict__ W2,
                 u16* __restrict__ pT,
                 u16* __restrict__ W1F,
                 u16* __restrict__ W2F) {
    int idx = blockIdx.x * 256 + threadIdx.x;
    const int total = BATCH * 3 * HP * HP;
    if (idx < total) {
        int xy = idx % (HP * HP);
        int bp = idx / (HP * HP);
        const float* src = planes + (size_t)bp * FEAT * HP * HP + xy;
        unsigned o16[16];
        #pragma unroll
        for (int k = 0; k < 16; ++k) {
            unsigned lo = __half_as_ushort(__float2half_rn(src[(size_t)(2*k)   * HP*HP]));
            unsigned hi = __half_as_ushort(__float2half_rn(src[(size_t)(2*k+1) * HP*HP]));
            o16[k] = lo | (hi << 16);
        }
        uint4* dst = (uint4*)(pT + (size_t)idx * FEAT);
        #pragma unroll
        for (int q = 0; q < 4; ++q)
            dst[q] = make_uint4(o16[4*q], o16[4*q+1], o16[4*q+2], o16[4*q+3]);
    } else {
        int r = idx - total;              // 0..255 (one tail block)
        // W1F: B-frag of (W1/3)[32 k][64 n]; e=(nt*64+l)*8+i holds
        // f16(W1[k=(l>>4)*8+i][n=nt*16+(l&15)] / 3)
        #pragma unroll
        for (int i = 0; i < 8; ++i) {
            int e = r * 8 + i;            // 0..2047
            int nt = e >> 9, ll = (e >> 3) & 63, ii = e & 7;
            int k = ((ll >> 4) << 3) + ii;
            int nn = (nt << 4) + (ll & 15);
            W1F[e] = __half_as_ushort(__float2half_rn(W1[k * HID + nn] * (1.f/3.f)));
        }
        // W2F: B-frag of W2 padded [64 k][16 n]
        if (r < 128) {
            #pragma unroll
            for (int i = 0; i < 8; ++i) {
                int e = r * 8 + i;        // 0..1023
                int kk = e >> 9, ll = (e >> 3) & 63, ii = e & 7;
                int k = kk * 32 + ((ll >> 4) << 3) + ii;
                int nn = ll & 15;
                W2F[e] = (nn < 4) ? __half_as_ushort(__float2half_rn(W2[k * 4 + nn]))
                                  : (u16)0;
            }
        }
    }
}

// ---- compute 4 corner offsets (u16 elements from pbase) + weights ------
__device__ __forceinline__ void plane_addr(float gx, float gy, int fc8, unsigned pofs,
                                           unsigned* __restrict__ offs,
                                           float* __restrict__ wts) {
    float px = fmaf(gx, 127.5f, 127.5f);   // (gx+1)*0.5*(HP-1)
    float py = fmaf(gy, 127.5f, 127.5f);
    float fx = floorf(px), fy = floorf(py);
    float wx = px - fx, wy = py - fy;
    int x0 = (int)fx, y0 = (int)fy;
    int x1 = x0 + 1, y1 = y0 + 1;
    bool vx0 = (unsigned)x0 < HP, vx1 = (unsigned)x1 < HP;
    bool vy0 = (unsigned)y0 < HP, vy1 = (unsigned)y1 < HP;
    int cx0 = min(max(x0, 0), HP-1), cx1 = min(max(x1, 0), HP-1);
    int cy0 = min(max(y0, 0), HP-1), cy1 = min(max(y1, 0), HP-1);
    unsigned a00 = (unsigned)(cy0 * HP + cx0) * FEAT + fc8 + pofs;
    unsigned dxe = (unsigned)(cx1 - cx0) * FEAT;        // 0 or 32
    unsigned dye = (unsigned)(cy1 - cy0) * (HP * FEAT); // 0 or 8192
    offs[0] = a00;
    offs[1] = a00 + dxe;
    offs[2] = a00 + dye;
    offs[3] = a00 + dye + dxe;
    wts[0] = (vx0 && vy0) ? (1.f-wx)*(1.f-wy) : 0.f;
    wts[1] = (vx1 && vy0) ? wx*(1.f-wy)       : 0.f;
    wts[2] = (vx0 && vy1) ? (1.f-wx)*wy       : 0.f;
    wts[3] = (vx1 && vy1) ? wx*wy             : 0.f;
}

// ---- fused: gather + f16 MFMA MLP + in-block composite -----------------
// block = 192 threads = 3 waves = 48 samples = EXACTLY ONE RAY.
// wave w: 16 samples; lane l: sample (l&15), feats (l>>4)*8..+7 == A-frag
// of mfma_f32_16x16x32_f16. C/D: row=4*(l>>4)+reg, col=l&15 (verified r7).
// launch_bounds(192,4): 128-VGPR budget so all 12 corner loads stay in flight.
__global__ __launch_bounds__(192, 4)
void render_mfma(const u16* __restrict__ pT,
                 const float* __restrict__ rayo,
                 const float* __restrict__ rayd,
                 const float* __restrict__ jitter,
                 const u16* __restrict__ W1F,
                 const u16* __restrict__ W2F,
                 const float* __restrict__ b1,
                 const float* __restrict__ b2,
                 float* __restrict__ out) {
    __shared__ __align__(16) u16 hlds[3][1024];  // per-wave 16x64 f16, XOR-swizzled
    __shared__ __align__(16) float4 s_smp[48];   // {dens,r,g,b} per sample
    __shared__ float s_sd[48];

    const int t = threadIdx.x;
    const int w = t >> 6;
    const int l = t & 63;
    const int c = l & 15;          // A-row / C-col (sample-in-wave)
    const int g = l >> 4;          // k-chunk / C row-group
    const int ray = blockIdx.x;    // one ray per block
    const int ls = w * 16 + c;     // local sample == n
    const int s  = ray * NS + ls;  // global sample
    const int b  = ray >> 12;

    const float jit = jitter[s];
    const float sd = fmaf((float)ls, S_DELTA, jit * S_DELTA);
    const float ox = rayo[ray*3+0], oy = rayo[ray*3+1], oz = rayo[ray*3+2];
    const float dx = rayd[ray*3+0], dy = rayd[ray*3+1], dz = rayd[ray*3+2];
    const float cxv = fmaf(sd, dx, ox);
    const float cyv = fmaf(sd, dy, oy);
    const float czv = fmaf(sd, dz, oz);

    // phase A: all 12 corner offsets + weights
    const int fc8 = g * 8;
    unsigned offs[12];
    float wts[12];
    plane_addr(cxv, cyv, fc8, 0u,          offs + 0, wts + 0);  // (x,y)
    plane_addr(cxv, czv, fc8, (unsigned)PSZ,     offs + 4, wts + 4);  // (x,z)
    plane_addr(cyv, czv, fc8, (unsigned)(2*PSZ), offs + 8, wts + 8);  // (y,z)

    // phase B: issue ALL 12 loads back-to-back (uniform SGPR base + voffset)
    const u16* pbase = pT + (size_t)b * 3 * PSZ;   // wave-uniform
    uint4 dat[12];
    #pragma unroll
    for (int i = 0; i < 12; ++i)
        dat[i] = *(const uint4*)(pbase + offs[i]);

    // phase C: consume — 3 independent per-plane chains (ILP)
    __half2 a0[4], a1[4], a2[4];
    #pragma unroll
    for (int i = 0; i < 4; ++i) {
        a0[i] = __float2half2_rn(0.f);
        a1[i] = __float2half2_rn(0.f);
        a2[i] = __float2half2_rn(0.f);
    }
    #pragma unroll
    for (int q = 0; q < 4; ++q) {
        union { uint4 u; __half2 h[4]; } d0, d1, d2;
        d0.u = dat[q]; d1.u = dat[4+q]; d2.u = dat[8+q];
        __half2 w0 = __float2half2_rn(wts[q]);
        __half2 w1 = __float2half2_rn(wts[4+q]);
        __half2 w2 = __float2half2_rn(wts[8+q]);
        #pragma unroll
        for (int j = 0; j < 4; ++j) {
            a0[j] = __hfma2(d0.h[j], w0, a0[j]);
            a1[j] = __hfma2(d1.h[j], w1, a1[j]);
            a2[j] = __hfma2(d2.h[j], w2, a2[j]);
        }
    }

    // sum planes -> A-frag (1/3 folded into W1F)
    union { __half2 h[4]; half8 v; } A;
    #pragma unroll
    for (int i = 0; i < 4; ++i)
        A.h[i] = __hadd2(__hadd2(a0[i], a1[i]), a2[i]);

    // layer 1: H[16 samples][64 hid] = X @ (W1/3) + b1 (bias in C-init)
    facc4 H[4];
    #pragma unroll
    for (int nt = 0; nt < 4; ++nt) {
        const float bb = b1[nt * 16 + c];          // C col = hid = nt*16+c
        facc4 Cb = {bb, bb, bb, bb};
        union { uint4 q; half8 v; } B;
        B.q = *(const uint4*)(W1F + (size_t)(nt * 64 + l) * 8);
        H[nt] = __builtin_amdgcn_mfma_f32_16x16x32_f16(A.v, B.v, Cb, 0, 0, 0);
    }

    // softplus -> f16 -> LDS (XOR swizzle: byte ^= (row&7)<<4)
    char* lb = (char*)&hlds[w][0];
    #pragma unroll
    for (int nt = 0; nt < 4; ++nt) {
        #pragma unroll
        for (int r = 0; r < 4; ++r) {
            const int row = g * 4 + r;                  // sample-in-wave
            const float hv = softplus_f(H[nt][r]);
            const int off = row * 128 + ((((nt * 16 + c) * 2)) ^ ((row & 7) << 4));
            *(u16*)(lb + off) = __half_as_ushort(__float2half_rn(hv));
        }
    }
    // wave-private LDS: compiler inserts lgkmcnt wait; no barrier needed.

    // layer 2: O[16][4] = softplus(H) @ W2 + b2 (bias in C-init; C col = c)
    const float bb2 = b2[c & 3];
    facc4 O = {bb2, bb2, bb2, bb2};
    #pragma unroll
    for (int kk = 0; kk < 2; ++kk) {
        union { uint4 q; half8 v; } A2;
        const int off = c * 128 + ((kk * 64 + g * 16) ^ ((c & 7) << 4));
        A2.q = *(const uint4*)(lb + off);
        union { uint4 q; half8 v; } B2;
        B2.q = *(const uint4*)(W2F + (size_t)(kk * 64 + l) * 8);
        O = __builtin_amdgcn_mfma_f32_16x16x32_f16(A2.v, B2.v, O, 0, 0, 0);
    }

    // epilogue: lane holds O[sample 4g+r][col c]; cols 0..3 valid -> LDS
    if (c < 4) {
        #pragma unroll
        for (int r = 0; r < 4; ++r) {
            const int li = w * 16 + g * 4 + r;
            const float o = O[r];
            const float val = (c == 0) ? softplus_f(o)
                                       : (sigmoid_f(o) * 1.002f - 0.001f);
            ((float*)&s_smp[li])[c] = val;
        }
    }
    if (g == 0) s_sd[ls] = sd;
    __syncthreads();

    // composite: wave 0 scans this block's ray (48 samples)
    if (w == 0) {
        const bool valid = l < NS;
        float4 v = make_float4(0.f, 0.f, 0.f, 0.f);
        float sdc = 0.f;
        if (valid) { v = s_smp[l]; sdc = s_sd[l]; }
        float sdn = __shfl_down(sdc, 1);

        float alpha = 0.f, lg = 0.f;
        if (valid) {
            float delta = (l < NS - 1) ? (sdn - sdc) : 1e10f;
            float tt = __expf(-delta * v.x);
            alpha = 1.0f - tt;
            lg = __logf(tt + 1e-10f);
        }
        float sacc = lg;
        #pragma unroll
        for (int off = 1; off < 64; off <<= 1) {
            float u = __shfl_up(sacc, off);
            if (l >= off) sacc += u;
        }
        float finalLog = __shfl(sacc, NS - 1);
        float T   = __expf(sacc - lg);
        float wgt = valid ? alpha * T : 0.f;

        float rf = wgt * v.y, gf = wgt * v.z, bf = wgt * v.w;
        float dep = wgt * sdc, wsum = wgt;
        #pragma unroll
        for (int off = 32; off; off >>= 1) {
            rf   += __shfl_xor(rf, off);
            gf   += __shfl_xor(gf, off);
            bf   += __shfl_xor(bf, off);
            dep  += __shfl_xor(dep, off);
            wsum += __shfl_xor(wsum, off);
        }
        if (l == 0) {
            out[ray * 3 + 0] = rf;
            out[ray * 3 + 1] = gf;
            out[ray * 3 + 2] = bf;
            out[NRAY * 3 + ray] = dep;
            out[NRAY * 4 + ray] = wsum;
            out[NRAY * 5 + ray] = __expf(finalLog);
        }
    }
}

// ---- fallback: fully fused fp32, direct plane layout -------------------
__global__ __launch_bounds__(192)
void render_fused(const float* __restrict__ pl,
                  const float* __restrict__ rayo,
                  const float* __restrict__ rayd,
                  const float* __restrict__ jitter,
                  const float* __restrict__ W1, const float* __restrict__ b1,
                  const float* __restrict__ W2, const float* __restrict__ b2,
                  float* __restrict__ out) {
    __shared__ float4 smpb[192];
    __shared__ float  sdsb[192];
    int tid = threadIdx.x;
    int lr  = tid / NS;
    int n   = tid - lr * NS;
    int ray = blockIdx.x * 4 + lr;
    int b   = ray >> 12;

    float jit = jitter[ray * NS + n];
    float sd  = (float)n * S_DELTA + jit * S_DELTA;
    float ox = rayo[ray*3+0], oy = rayo[ray*3+1], oz = rayo[ray*3+2];
    float dx = rayd[ray*3+0], dy = rayd[ray*3+1], dz = rayd[ray*3+2];
    float cx = fmaf(sd, dx, ox), cy = fmaf(sd, dy, oy), cz = fmaf(sd, dz, oz);

    float xv[32];
    #pragma unroll
    for (int i = 0; i < 32; ++i) xv[i] = 0.f;
    const size_t psz = (size_t)HP * HP * FEAT;
    const float* base = pl + (size_t)b * 3 * psz;
    float gxs[3] = {cx, cx, cy}, gys[3] = {cy, cz, cz};
    for (int p = 0; p < 3; ++p) {
        float px = (gxs[p] + 1.0f) * 0.5f * (float)(HP - 1);
        float py = (gys[p] + 1.0f) * 0.5f * (float)(HP - 1);
        float fx = floorf(px), fy = floorf(py);
        float wx = px - fx, wy = py - fy;
        int x0 = (int)fx, y0 = (int)fy, x1 = x0 + 1, y1 = y0 + 1;
        const float* pb = base + p * psz;
        float ws[4] = {(1.f-wx)*(1.f-wy), wx*(1.f-wy), (1.f-wx)*wy, wx*wy};
        int xs[4] = {x0, x1, x0, x1}, ys[4] = {y0, y0, y1, y1};
        for (int q = 0; q < 4; ++q) {
            if ((unsigned)xs[q] < HP && (unsigned)ys[q] < HP) {
                const float* pp = pb + (size_t)ys[q] * HP + xs[q];
                #pragma unroll
                for (int f = 0; f < 32; ++f)
                    xv[f] = fmaf(ws[q], pp[(size_t)f * HP * HP], xv[f]);
            }
        }
    }
    #pragma unroll
    for (int i = 0; i < 32; ++i) xv[i] *= (1.f/3.f);

    float o0 = b2[0], o1 = b2[1], o2 = b2[2], o3 = b2[3];
    #pragma unroll
    for (int j = 0; j < HID; ++j) {
        float hj = b1[j];
        #pragma unroll
        for (int f = 0; f < FEAT; ++f) hj = fmaf(xv[f], W1[f * HID + j], hj);
        hj = softplus_f(hj);
        o0 = fmaf(hj, W2[j*4+0], o0);
        o1 = fmaf(hj, W2[j*4+1], o1);
        o2 = fmaf(hj, W2[j*4+2], o2);
        o3 = fmaf(hj, W2[j*4+3], o3);
    }
    smpb[tid] = make_float4(softplus_f(o0),
                            sigmoid_f(o1) * 1.002f - 0.001f,
                            sigmoid_f(o2) * 1.002f - 0.001f,
                            sigmoid_f(o3) * 1.002f - 0.001f);
    sdsb[tid] = sd;
    __syncthreads();

    if (tid < 4) {
        int rray = blockIdx.x * 4 + tid;
        const float4* sp  = &smpb[tid * NS];
        const float*  sdp = &sdsb[tid * NS];
        float T = 1.0f, rf = 0.f, gf = 0.f, bfv = 0.f, dep = 0.f, wsum = 0.f;
        for (int m = 0; m < NS; ++m) {
            float4 vv = sp[m];
            float sdc = sdp[m];
            float delta = (m < NS - 1) ? (sdp[m+1] - sdc) : 1e10f;
            float alpha = 1.0f - __expf(-delta * vv.x);
            float wq = alpha * T;
            rf = fmaf(wq, vv.y, rf);
            gf = fmaf(wq, vv.z, gf);
            bfv = fmaf(wq, vv.w, bfv);
            dep = fmaf(wq, sdc, dep);
            wsum += wq;
            T *= (1.0f - alpha + 1e-10f);
        }
        out[rray*3+0] = rf;
        out[rray*3+1] = gf;
        out[rray*3+2] = bfv;
        out[NRAY*3 + rray] = dep;
        out[NRAY*4 + rray] = wsum;
        out[NRAY*5 + rray] = T;
    }
}

extern "C" void kernel_launch(void* const* d_in, const int* in_sizes, int n_in,
                              void* d_out, int out_size, void* d_ws, size_t ws_size,
                              hipStream_t stream) {
    const float* planes = (const float*)d_in[0];
    const float* rayo   = (const float*)d_in[1];
    const float* rayd   = (const float*)d_in[2];
    const float* jitter = (const float*)d_in[3];
    const float* W1     = (const float*)d_in[4];
    const float* b1     = (const float*)d_in[5];
    const float* W2     = (const float*)d_in[6];
    const float* b2     = (const float*)d_in[7];
    float* out = (float*)d_out;

    const size_t pT_bytes = (size_t)BATCH * 3 * HP * HP * FEAT * 2;  // 25.2 MB f16
    const size_t w1f_off  = pT_bytes;
    const size_t w2f_off  = w1f_off + (size_t)FEAT * HID * 2;  // 4 KB
    const size_t need     = w2f_off + (size_t)HID * 16 * 2;    // +2 KB

    if (ws_size >= need) {
        char* ws = (char*)d_ws;
        u16* pT  = (u16*)ws;
        u16* W1F = (u16*)(ws + w1f_off);
        u16* W2F = (u16*)(ws + w2f_off);
        const int tgrid = BATCH * 3 * HP * HP / 256 + 1;
        hipLaunchKernelGGL(prep_kernel, dim3(tgrid), dim3(256), 0, stream,
                           planes, W1, W2, pT, W1F, W2F);
        hipLaunchKernelGGL(render_mfma, dim3(NRAY), dim3(192), 0, stream,
                           pT, rayo, rayd, jitter, W1F, W2F, b1, b2, out);
    } else {
        hipLaunchKernelGGL(render_fused, dim3(NRAY / 4), dim3(192), 0, stream,
                           planes, rayo, rayd, jitter, W1, b1, W2, b2, out);
    }
}